// Round 12
// baseline (26840.707 us; speedup 1.0000x reference)
//
#include <hip/hip_runtime.h>
#include <hip/hip_bf16.h>

typedef unsigned int u32;
typedef unsigned long long u64;
typedef unsigned short u16;

#define NIMG 2
#define CCH 256
#define PIX 10000
#define NANCH 90000
#define PRENMS_N 2000
#define TOPK_N 1000
#define BBOX_CLIP_D 4.1351665567423558145
#define TP 24
#define BK 32

// ---------------------------------------------------------------- prep weights
__global__ void prep_weights(const float* __restrict__ conv_w,
                             const float* __restrict__ cls_w, const float* __restrict__ box_w,
                             const float* __restrict__ cls_b, const float* __restrict__ box_b,
                             float* __restrict__ wt, float* __restrict__ wh, float* __restrict__ hb)
{
    int i = blockIdx.x * 256 + threadIdx.x;
    if (i < 2304 * 256) {
        int oc = i & 255;
        int k  = i >> 8;
        int ci = k & 255, kid = k >> 8;
        wt[i] = conv_w[(oc * 256 + ci) * 9 + kid];
    }
    int j = i - 2304 * 256;
    if (j >= 0 && j < 256 * 48) {
        int oc = j % 48, c = j / 48;
        float v = 0.f;
        if (oc < 9) v = cls_w[oc * 256 + c];
        else if (oc < 45) v = box_w[(oc - 9) * 256 + c];
        wh[j] = v;
    }
    int h = i - (2304 * 256 + 256 * 48);
    if (h >= 0 && h < 48) {
        float v = 0.f;
        if (h < 9) v = cls_b[h];
        else if (h < 45) v = box_b[h - 9];
        hb[h] = v;
    }
}

// ---------------------------------------------------------------- fused conv3x3+relu+heads (f64)
struct ConvStage { double As[BK][TP]; float Bs[BK][256]; };
union ShBuf { ConvStage cv; double Ls[TP][258]; };

__global__ __launch_bounds__(256) void conv_heads(
    const float* __restrict__ feat, const float* __restrict__ wt, const float* __restrict__ conv_b,
    const float* __restrict__ wh, const float* __restrict__ hb,
    double* __restrict__ logits, double* __restrict__ deltas)
{
    __shared__ ShBuf u;
    const int t  = threadIdx.x;
    const int p0 = blockIdx.x * TP;
    const int b  = blockIdx.y;
    double acc[TP] = {};

    for (int k0 = 0; k0 < 2304; k0 += BK) {
#pragma unroll
        for (int r = 0; r < 3; ++r) {
            int e  = t + 256 * r;
            int kk = e / TP, px = e - kk * TP;
            int kg = k0 + kk;
            int ci = kg & 255, kid = kg >> 8;
            int ky = (kid >= 6) ? 2 : (kid >= 3 ? 1 : 0);
            int kx = kid - ky * 3;
            int p = p0 + px;
            float v = 0.f;
            if (p < PIX) {
                int y = p / 100, x = p - y * 100;
                int iy = y + ky - 1, ix = x + kx - 1;
                if ((u32)iy < 100u && (u32)ix < 100u)
                    v = feat[((size_t)(b * CCH + ci) * 100 + iy) * 100 + ix];
            }
            u.cv.As[kk][px] = (double)v;
        }
#pragma unroll
        for (int r = 0; r < 32; ++r) {
            int e  = t + 256 * r;
            int kk = e >> 8, oc = e & 255;
            u.cv.Bs[kk][oc] = wt[(size_t)(k0 + kk) * 256 + oc];
        }
        __syncthreads();
        for (int kk = 0; kk < BK; ++kk) {
            double bv = (double)u.cv.Bs[kk][t];
#pragma unroll
            for (int h = 0; h < TP / 2; ++h) {
                double2 a2 = *(const double2*)&u.cv.As[kk][h * 2];
                acc[h * 2]     += a2.x * bv;
                acc[h * 2 + 1] += a2.y * bv;
            }
        }
        __syncthreads();
    }
    double cbv = (double)conv_b[t];
#pragma unroll
    for (int px = 0; px < TP; ++px)
        u.Ls[px][t] = fmax(acc[px] + cbv, 0.0);
    __syncthreads();
    if (t < TP * 8) {
        int px = t >> 3, j = t & 7;
        int p = p0 + px;
        if (p < PIX) {
            for (int k = 0; k < 6; ++k) {
                int oc = j + 8 * k;
                double s = (double)hb[oc];
                for (int c = 0; c < 256; ++c)
                    s += u.Ls[px][c] * (double)wh[c * 48 + oc];
                if (oc < 9)
                    logits[(size_t)b * NANCH + p * 9 + oc] = s;
                else if (oc < 45)
                    deltas[(size_t)b * NANCH * 4 + p * 36 + (oc - 9)] = s;
            }
        }
    }
}

// ---------------------------------------------------------------- decode: f32-cast deltas, f64 math,
// score = f32 op-sequence sigmoid of f32-CAST logit (CR exp, f32 add, f32 div)
__global__ void decode_anchors(
    const double* __restrict__ logits, const double* __restrict__ deltas,
    const int* __restrict__ shapes,
    double* __restrict__ boxes, u32* __restrict__ validf, u64* __restrict__ km)
{
    int gid = blockIdx.x * 256 + threadIdx.x;
    if (gid >= NIMG * NANCH) return;
    int b = gid / NANCH, idx = gid - b * NANCH;
    int p = idx / 9, a = idx - p * 9;
    int y = p / 100, x = p - y * 100;
    int si = a % 3, ri = a / 3;
    double scale = (si == 0) ? 128.0 : ((si == 1) ? 256.0 : 512.0);
    double ratio = (ri == 0) ? 0.5 : ((ri == 1) ? 1.0 : 2.0);
    double hr = sqrt(ratio), wr = 1.0 / hr;
    double wsv = wr * scale, hsv = hr * scale;
    double sx = x * 16.0, sy = y * 16.0;
    double ax1 = sx + rint(-wsv * 0.5), ay1 = sy + rint(-hsv * 0.5);
    double ax2 = sx + rint(wsv * 0.5),  ay2 = sy + rint(hsv * 0.5);
    double wa = ax2 - ax1, ha = ay2 - ay1;
    double cxa = ax1 + 0.5 * wa, cya = ay1 + 0.5 * ha;
    double4 d = *(const double4*)&deltas[((size_t)b * NANCH + idx) * 4];
    // mirror the reference's f32 dtype: cast deltas to f32 first
    float dxf = (float)d.x, dyf = (float)d.y;
    float dwf = fminf((float)d.z, (float)BBOX_CLIP_D);
    float dhf = fminf((float)d.w, (float)BBOX_CLIP_D);
    double cx = (double)dxf * wa + cxa, cy = (double)dyf * ha + cya;
    double w = exp((double)dwf) * wa, h = exp((double)dhf) * ha;
    double x1 = cx - 0.5 * w, y1 = cy - 0.5 * h, x2 = cx + 0.5 * w, y2 = cy + 0.5 * h;
    double him = (double)shapes[b * 2 + 0], wim = (double)shapes[b * 2 + 1];
    x1 = fmin(fmax(x1, 0.0), wim); y1 = fmin(fmax(y1, 0.0), him);
    x2 = fmin(fmax(x2, 0.0), wim); y2 = fmin(fmax(y2, 0.0), him);
    u32 valid = ((x2 - x1 >= 16.0) && (y2 - y1 >= 16.0)) ? 1u : 0u;
    // score: f32-cast logit -> CR f32 exp -> f32 add -> f32 div (np f32 op sequence)
    float l32 = (float)logits[(size_t)b * NANCH + idx];
    float e32 = (float)exp(-(double)l32);   // correctly-rounded f32 exp of f32 input
    float den = 1.0f + e32;                 // IEEE f32 add
    float s32 = 1.0f / den;                 // IEEE f32 div
    u32 kh = __float_as_uint(s32);
    double4 bx; bx.x = x1; bx.y = y1; bx.z = x2; bx.w = y2;
    *(double4*)&boxes[((size_t)b * NANCH + idx) * 4] = bx;
    validf[gid] = valid;
    km[gid] = ((u64)kh << 32) | (u32)(~(u32)idx);   // score desc, ties idx asc (stable top_k)
}

// ---------------------------------------------------------------- brute-force top-2000
__global__ __launch_bounds__(1024) void sel2000(u64* __restrict__ km,
                                                u64* __restrict__ selkey, u32* __restrict__ selidx)
{
    __shared__ u64 red[1024];
    int b = blockIdx.x, t = threadIdx.x;
    u64* k = km + (size_t)b * NANCH;
    for (int r = 0; r < PRENMS_N; ++r) {
        u64 best = 0;
        for (int i = t; i < NANCH; i += 1024) {
            u64 v = k[i];
            if (v > best) best = v;
        }
        red[t] = best;
        __syncthreads();
        for (int s = 512; s > 0; s >>= 1) {
            if (t < s && red[t + s] > red[t]) red[t] = red[t + s];
            __syncthreads();
        }
        if (t == 0) {
            u64 wk = red[0];
            u32 idx = ~(u32)wk;
            selkey[b * PRENMS_N + r] = wk;
            selidx[b * PRENMS_N + r] = idx;
            k[idx] = 0ull;
        }
        __syncthreads();
    }
}

// ---------------------------------------------------------------- brute-force sequential NMS (f64)
__global__ __launch_bounds__(256) void nms_brute(
    const u32* __restrict__ selidx, const double* __restrict__ boxes,
    const u32* __restrict__ validf, u32* __restrict__ kept)
{
    __shared__ unsigned char supp[PRENMS_N];
    int b = blockIdx.x, t = threadIdx.x;
    for (int e = t; e < PRENMS_N; e += 256) {
        u32 idx = selidx[b * PRENMS_N + e];
        supp[e] = validf[(size_t)b * NANCH + idx] ? 0 : 1;
    }
    __syncthreads();
    for (int i = 0; i < PRENMS_N; ++i) {
        if (!supp[i]) {
            u32 ii = selidx[b * PRENMS_N + i];
            double4 bi = *(const double4*)&boxes[((size_t)b * NANCH + ii) * 4];
            double ai = (bi.z - bi.x) * (bi.w - bi.y);
            for (int j = i + 1 + t; j < PRENMS_N; j += 256) {
                u32 jj = selidx[b * PRENMS_N + j];
                double4 bj = *(const double4*)&boxes[((size_t)b * NANCH + jj) * 4];
                double aj = (bj.z - bj.x) * (bj.w - bj.y);
                double lx = fmax(bi.x, bj.x), ly = fmax(bi.y, bj.y);
                double rx = fmin(bi.z, bj.z), ry = fmin(bi.w, bj.w);
                double iw = fmax(rx - lx, 0.0), ih = fmax(ry - ly, 0.0);
                double inter = iw * ih;
                double iou = inter / (ai + aj - inter + 1e-9);
                if (iou > 0.7) supp[j] = 1;
            }
        }
        __syncthreads();
    }
    for (int e = t; e < PRENMS_N; e += 256) kept[b * 2048 + e] = supp[e] ? 0u : 1u;
}

// ---------------------------------------------------------------- finalize (stable top_k semantics)
__global__ __launch_bounds__(256) void finalize_brute(
    const u32* __restrict__ kept, const u64* __restrict__ selkey, const u32* __restrict__ selidx,
    const double* __restrict__ boxes, float* __restrict__ out)
{
    __shared__ u16 rowOf[PRENMS_N];
    __shared__ u32 nkS;
    int b = blockIdx.x, t = threadIdx.x;
    if (t == 0) {
        int nk = 0;
        for (int e = 0; e < PRENMS_N; ++e)
            rowOf[e] = kept[b * 2048 + e] ? (u16)(nk++) : (u16)0xFFFF;
        nkS = (u32)nk;
        int pos = nk;
        for (int e = 0; e < PRENMS_N; ++e)
            if (rowOf[e] == 0xFFFF) rowOf[e] = (u16)(pos++);
    }
    __syncthreads();
    u32 nk = nkS;
    for (int e = t; e < PRENMS_N; e += 256) {
        u32 r = rowOf[e];
        if (r < TOPK_N) {
            u32 idx = selidx[b * PRENMS_N + e];
            double4 bx = *(const double4*)&boxes[((size_t)b * NANCH + idx) * 4];
            float4 fo = make_float4((float)bx.x, (float)bx.y, (float)bx.z, (float)bx.w);
            *(float4*)&out[((size_t)b * TOPK_N + r) * 4] = fo;
            float sc = (r < nk) ? __uint_as_float((u32)(selkey[b * PRENMS_N + e] >> 32)) : -1.0f;
            out[(size_t)NIMG * TOPK_N * 4 + b * TOPK_N + r] = sc;
        }
    }
}

// ---------------------------------------------------------------- flood (host-detected config errors)
__global__ void flood(float* __restrict__ out, u32 hostbits)
{
    if (hostbits == 0u) return;
    int bit = __ffs(hostbits) - 1;
    float c = 60000.f + 4000.f * (float)bit;
    int i = blockIdx.x * 256 + threadIdx.x;
    if (i < NIMG * TOPK_N * 5) out[i] = c;
}

// ================================================================ launch
extern "C" void kernel_launch(void* const* d_in, const int* in_sizes, int n_in,
                              void* d_out, int out_size, void* d_ws, size_t ws_size,
                              hipStream_t stream)
{
    float* out = (float*)d_out;
    char* ws = (char*)d_ws;

    const float *feat = nullptr, *conv_w = nullptr, *conv_b = nullptr;
    const float *cls_w = nullptr, *cls_b = nullptr, *box_w = nullptr, *box_b = nullptr;
    const int* shapes = nullptr;
    for (int i = 0; i < n_in; ++i) {
        switch (in_sizes[i]) {
            case 5120000:  feat   = (const float*)d_in[i]; break;
            case 4:        shapes = (const int*)d_in[i]; break;
            case 589824:   conv_w = (const float*)d_in[i]; break;
            case 256:      conv_b = (const float*)d_in[i]; break;
            case 2304:     cls_w  = (const float*)d_in[i]; break;
            case 9:        cls_b  = (const float*)d_in[i]; break;
            case 9216:     box_w  = (const float*)d_in[i]; break;
            case 36:       box_b  = (const float*)d_in[i]; break;
            default: break;
        }
    }
    u32 hostbits = 0;
    if (!feat || !shapes || !conv_w || !conv_b || !cls_w || !cls_b || !box_w || !box_b)
        hostbits |= 2u;

    size_t off = 0;
    auto take = [&](size_t bytes) { size_t o = off; off += (bytes + 255) & ~(size_t)255; return o; };
    size_t off_wt     = take((size_t)2304 * 256 * 4);
    size_t off_wh     = take((size_t)256 * 48 * 4);
    size_t off_hb     = take(256);
    size_t off_logit  = take((size_t)NIMG * NANCH * 8);
    size_t off_delta  = take((size_t)NIMG * NANCH * 4 * 8);
    size_t off_boxes  = take((size_t)NIMG * NANCH * 4 * 8);
    size_t off_valid  = take((size_t)NIMG * NANCH * 4);
    size_t off_km     = take((size_t)NIMG * NANCH * 8);
    size_t off_selkey = take((size_t)NIMG * PRENMS_N * 8);
    size_t off_selidx = take((size_t)NIMG * PRENMS_N * 4);
    size_t off_kept   = take((size_t)NIMG * 2048 * 4);
    if (ws_size < off) hostbits |= 1u;

    float*  wt     = (float*) (ws + off_wt);
    float*  wh     = (float*) (ws + off_wh);
    float*  hb     = (float*) (ws + off_hb);
    double* logit  = (double*)(ws + off_logit);
    double* delta  = (double*)(ws + off_delta);
    double* boxes  = (double*)(ws + off_boxes);
    u32*    validf = (u32*)   (ws + off_valid);
    u64*    km     = (u64*)   (ws + off_km);
    u64*    selkey = (u64*)   (ws + off_selkey);
    u32*    selidx = (u32*)   (ws + off_selidx);
    u32*    kept   = (u32*)   (ws + off_kept);

    if (hostbits != 0) {
        flood<<<40, 256, 0, stream>>>(out, hostbits);
        return;
    }

    prep_weights<<<(2304 * 256 + 256 * 48 + 48 + 255) / 256, 256, 0, stream>>>(
        conv_w, cls_w, box_w, cls_b, box_b, wt, wh, hb);

    conv_heads<<<dim3((PIX + TP - 1) / TP, NIMG), 256, 0, stream>>>(
        feat, wt, conv_b, wh, hb, logit, delta);

    decode_anchors<<<(NIMG * NANCH + 255) / 256, 256, 0, stream>>>(
        logit, delta, shapes, boxes, validf, km);

    sel2000<<<NIMG, 1024, 0, stream>>>(km, selkey, selidx);

    nms_brute<<<NIMG, 256, 0, stream>>>(selidx, boxes, validf, kept);

    finalize_brute<<<NIMG, 256, 0, stream>>>(kept, selkey, selidx, boxes, out);
}

// Round 13
// 2610.998 us; speedup vs baseline: 10.2799x; 10.2799x over previous
//
#include <hip/hip_runtime.h>
#include <hip/hip_bf16.h>

typedef unsigned int u32;
typedef unsigned long long u64;
typedef unsigned short u16;

#define NIMG 2
#define CCH 256
#define PIX 10000
#define NANCH 90000
#define PRENMS_N 2000
#define TOPK_N 1000
#define CAND_CAP 4096
#define BBOX_CLIP_D 4.1351665567423558145
#define TP 24
#define BK 32

// ---------------------------------------------------------------- prep weights
__global__ void prep_weights(const float* __restrict__ conv_w,
                             const float* __restrict__ cls_w, const float* __restrict__ box_w,
                             const float* __restrict__ cls_b, const float* __restrict__ box_b,
                             float* __restrict__ wt, float* __restrict__ wh, float* __restrict__ hb)
{
    int i = blockIdx.x * 256 + threadIdx.x;
    if (i < 2304 * 256) {
        int oc = i & 255;
        int k  = i >> 8;
        int ci = k & 255, kid = k >> 8;
        wt[i] = conv_w[(oc * 256 + ci) * 9 + kid];
    }
    int j = i - 2304 * 256;
    if (j >= 0 && j < 256 * 48) {
        int oc = j % 48, c = j / 48;
        float v = 0.f;
        if (oc < 9) v = cls_w[oc * 256 + c];
        else if (oc < 45) v = box_w[(oc - 9) * 256 + c];
        wh[j] = v;
    }
    int h = i - (2304 * 256 + 256 * 48);
    if (h >= 0 && h < 48) {
        float v = 0.f;
        if (h < 9) v = cls_b[h];
        else if (h < 45) v = box_b[h - 9];
        hb[h] = v;
    }
}

// ---------------------------------------------------------------- fused conv3x3+relu+heads (f64) [verified]
struct ConvStage { double As[BK][TP]; float Bs[BK][256]; };
union ShBuf { ConvStage cv; double Ls[TP][258]; };

__global__ __launch_bounds__(256) void conv_heads(
    const float* __restrict__ feat, const float* __restrict__ wt, const float* __restrict__ conv_b,
    const float* __restrict__ wh, const float* __restrict__ hb,
    double* __restrict__ logits, double* __restrict__ deltas)
{
    __shared__ ShBuf u;
    const int t  = threadIdx.x;
    const int p0 = blockIdx.x * TP;
    const int b  = blockIdx.y;
    double acc[TP] = {};

    for (int k0 = 0; k0 < 2304; k0 += BK) {
#pragma unroll
        for (int r = 0; r < 3; ++r) {
            int e  = t + 256 * r;
            int kk = e / TP, px = e - kk * TP;
            int kg = k0 + kk;
            int ci = kg & 255, kid = kg >> 8;
            int ky = (kid >= 6) ? 2 : (kid >= 3 ? 1 : 0);
            int kx = kid - ky * 3;
            int p = p0 + px;
            float v = 0.f;
            if (p < PIX) {
                int y = p / 100, x = p - y * 100;
                int iy = y + ky - 1, ix = x + kx - 1;
                if ((u32)iy < 100u && (u32)ix < 100u)
                    v = feat[((size_t)(b * CCH + ci) * 100 + iy) * 100 + ix];
            }
            u.cv.As[kk][px] = (double)v;
        }
#pragma unroll
        for (int r = 0; r < 32; ++r) {
            int e  = t + 256 * r;
            int kk = e >> 8, oc = e & 255;
            u.cv.Bs[kk][oc] = wt[(size_t)(k0 + kk) * 256 + oc];
        }
        __syncthreads();
        for (int kk = 0; kk < BK; ++kk) {
            double bv = (double)u.cv.Bs[kk][t];
#pragma unroll
            for (int h = 0; h < TP / 2; ++h) {
                double2 a2 = *(const double2*)&u.cv.As[kk][h * 2];
                acc[h * 2]     += a2.x * bv;
                acc[h * 2 + 1] += a2.y * bv;
            }
        }
        __syncthreads();
    }
    double cbv = (double)conv_b[t];
#pragma unroll
    for (int px = 0; px < TP; ++px)
        u.Ls[px][t] = fmax(acc[px] + cbv, 0.0);
    __syncthreads();
    if (t < TP * 8) {
        int px = t >> 3, j = t & 7;
        int p = p0 + px;
        if (p < PIX) {
            for (int k = 0; k < 6; ++k) {
                int oc = j + 8 * k;
                double s = (double)hb[oc];
                for (int c = 0; c < 256; ++c)
                    s += u.Ls[px][c] * (double)wh[c * 48 + oc];
                if (oc < 9)
                    logits[(size_t)b * NANCH + p * 9 + oc] = s;
                else if (oc < 45)
                    deltas[(size_t)b * NANCH * 4 + p * 36 + (oc - 9)] = s;
            }
        }
    }
}

// ---------------------------------------------------------------- decode [verified numerics] + hist1
__global__ void decode_anchors(
    const double* __restrict__ logits, const double* __restrict__ deltas,
    const int* __restrict__ shapes,
    double* __restrict__ boxes, u32* __restrict__ validf, u64* __restrict__ km,
    u32* __restrict__ hist1)
{
    int gid = blockIdx.x * 256 + threadIdx.x;
    if (gid >= NIMG * NANCH) return;
    int b = gid / NANCH, idx = gid - b * NANCH;
    int p = idx / 9, a = idx - p * 9;
    int y = p / 100, x = p - y * 100;
    int si = a % 3, ri = a / 3;
    double scale = (si == 0) ? 128.0 : ((si == 1) ? 256.0 : 512.0);
    double ratio = (ri == 0) ? 0.5 : ((ri == 1) ? 1.0 : 2.0);
    double hr = sqrt(ratio), wr = 1.0 / hr;
    double wsv = wr * scale, hsv = hr * scale;
    double sx = x * 16.0, sy = y * 16.0;
    double ax1 = sx + rint(-wsv * 0.5), ay1 = sy + rint(-hsv * 0.5);
    double ax2 = sx + rint(wsv * 0.5),  ay2 = sy + rint(hsv * 0.5);
    double wa = ax2 - ax1, ha = ay2 - ay1;
    double cxa = ax1 + 0.5 * wa, cya = ay1 + 0.5 * ha;
    double4 d = *(const double4*)&deltas[((size_t)b * NANCH + idx) * 4];
    float dxf = (float)d.x, dyf = (float)d.y;
    float dwf = fminf((float)d.z, (float)BBOX_CLIP_D);
    float dhf = fminf((float)d.w, (float)BBOX_CLIP_D);
    double cx = (double)dxf * wa + cxa, cy = (double)dyf * ha + cya;
    double w = exp((double)dwf) * wa, h = exp((double)dhf) * ha;
    double x1 = cx - 0.5 * w, y1 = cy - 0.5 * h, x2 = cx + 0.5 * w, y2 = cy + 0.5 * h;
    double him = (double)shapes[b * 2 + 0], wim = (double)shapes[b * 2 + 1];
    x1 = fmin(fmax(x1, 0.0), wim); y1 = fmin(fmax(y1, 0.0), him);
    x2 = fmin(fmax(x2, 0.0), wim); y2 = fmin(fmax(y2, 0.0), him);
    u32 valid = ((x2 - x1 >= 16.0) && (y2 - y1 >= 16.0)) ? 1u : 0u;
    float l32 = (float)logits[(size_t)b * NANCH + idx];
    float e32 = (float)exp(-(double)l32);
    float den = 1.0f + e32;
    float s32 = 1.0f / den;
    u32 kh = __float_as_uint(s32);
    double4 bx; bx.x = x1; bx.y = y1; bx.z = x2; bx.w = y2;
    *(double4*)&boxes[((size_t)b * NANCH + idx) * 4] = bx;
    validf[gid] = valid;
    km[gid] = ((u64)kh << 32) | (u32)(~(u32)idx);   // score desc, ties idx asc
    atomicAdd(&hist1[b * 65536 + (kh >> 16)], 1u);
}

// ---------------------------------------------------------------- two-level radix threshold
__global__ __launch_bounds__(1024) void scan_hist(const u32* __restrict__ hist, u32* scal, int level)
{
    __shared__ u32 part[1024];
    int b = blockIdx.x, t = threadIdx.x;
    const u32* h = hist + b * 65536;
    u32 s = 0;
    for (int c = 0; c < 64; ++c) s += h[t * 64 + c];
    part[t] = s; __syncthreads();
    for (int d = 1; d < 1024; d <<= 1) {
        u32 v = part[t] + ((t + d < 1024) ? part[t + d] : 0u);
        __syncthreads(); part[t] = v; __syncthreads();
    }
    u32 base  = (level == 1) ? 0u : scal[2 + b];
    u32 sfx1  = (t < 1023) ? part[t + 1] : 0u;
    u32 above = base + sfx1;
    u32 mine  = part[t] - sfx1;
    if (above < PRENMS_N && above + mine >= PRENMS_N) {
        u32 cum = above;
        for (int c = 63; c >= 0; --c) {
            u32 hv = h[t * 64 + c];
            if (cum + hv >= PRENMS_N) {
                int bin = t * 64 + c;
                if (level == 1) { scal[0 + b] = (u32)bin; scal[2 + b] = cum; }
                else            { scal[4 + b] = (scal[0 + b] << 16) | (u32)bin; scal[6 + b] = cum; }
                break;
            }
            cum += hv;
        }
    }
}

__global__ void build_hist2(const u64* __restrict__ km, const u32* __restrict__ scal,
                            u32* __restrict__ hist2)
{
    int gid = blockIdx.x * 256 + threadIdx.x;
    if (gid >= NIMG * NANCH) return;
    int b = gid / NANCH;
    u32 kh = (u32)(km[gid] >> 32);
    if ((kh >> 16) == scal[0 + b])
        atomicAdd(&hist2[b * 65536 + (kh & 0xFFFFu)], 1u);
}

__global__ void compact_cand(const u64* __restrict__ km, u32* scal, u64* __restrict__ ck)
{
    int gid = blockIdx.x * 256 + threadIdx.x;
    if (gid >= NIMG * NANCH) return;
    int b = gid / NANCH;
    u64 key = km[gid];
    u32 kh = (u32)(key >> 32);
    if (kh >= scal[4 + b]) {
        u32 pos = atomicAdd(&scal[8 + b], 1u);
        if (pos < CAND_CAP) ck[(size_t)b * CAND_CAP + pos] = key;
    }
}

// ---------------------------------------------------------------- bitonic sort 4096 (unique keys) + select
__global__ __launch_bounds__(1024) void sort_select(
    const u64* __restrict__ ck, const u32* __restrict__ scal,
    const double* __restrict__ boxes, const u32* __restrict__ validf,
    double* __restrict__ selbox, u32* __restrict__ selvl,
    u64* __restrict__ selkey, u32* __restrict__ selidx)
{
    __shared__ u64 sk[4096];
    int b = blockIdx.x, t = threadIdx.x;
    u32 n = scal[8 + b]; if (n > CAND_CAP) n = CAND_CAP;
    for (int i = t; i < 4096; i += 1024)
        sk[i] = (i < (int)n) ? ck[(size_t)b * CAND_CAP + i] : 0ull;
    __syncthreads();
    for (int k = 2; k <= 4096; k <<= 1) {
        for (int j = k >> 1; j > 0; j >>= 1) {
            for (int u2 = t; u2 < 2048; u2 += 1024) {
                int i  = (u2 / j) * (2 * j) + (u2 % j);
                int p2 = i + j;
                bool up = ((i & k) == 0);
                u64 ka = sk[i], kc = sk[p2];
                bool sw = up ? (kc > ka) : (ka > kc);
                if (sw) { sk[i] = kc; sk[p2] = ka; }
            }
            __syncthreads();
        }
    }
    for (int e = t; e < PRENMS_N; e += 1024) {
        u64 key = sk[e];
        u32 idx = ~(u32)key;
        selkey[b * 2048 + e] = key;
        u32 g = (idx >= NANCH) ? 0u : idx;
        selidx[b * 2048 + e] = g;
        double4 bx = *(const double4*)&boxes[((size_t)b * NANCH + g) * 4];
        *(double4*)&selbox[((size_t)b * 2048 + e) * 4] = bx;
        selvl[b * 2048 + e] = (idx >= NANCH) ? 0u : validf[(size_t)b * NANCH + g];
    }
    for (int e = PRENMS_N + t; e < 2048; e += 1024) {
        double4 z; z.x = 0.0; z.y = 0.0; z.z = 0.0; z.w = 0.0;
        *(double4*)&selbox[((size_t)b * 2048 + e) * 4] = z;
        selvl[b * 2048 + e] = 0u;
        selkey[b * 2048 + e] = 0ull;
        selidx[b * 2048 + e] = 0u;
    }
}

// ---------------------------------------------------------------- selection certificates (tripwire)
__global__ void count_sel(const u64* __restrict__ km, const u64* __restrict__ selkey, u32* scal)
{
    int gid = blockIdx.x * 256 + threadIdx.x;
    if (gid >= NIMG * NANCH) return;
    int b = gid / NANCH;
    if (km[gid] > selkey[b * 2048 + 1999]) atomicAdd(&scal[12 + b], 1u);
}

__global__ __launch_bounds__(256) void verify_sel(const u64* __restrict__ selkey,
                                                  const u32* __restrict__ scal, u32* flags)
{
    int b = blockIdx.x, t = threadIdx.x;
    for (int e = t; e < PRENMS_N - 1; e += 256)
        if (!(selkey[b * 2048 + e] > selkey[b * 2048 + e + 1])) atomicOr(flags, 4u);
    if (t == 0) {
        u32 n = scal[8 + b];
        if (n < PRENMS_N || n > CAND_CAP) atomicOr(flags, 1u);
        if (scal[12 + b] != PRENMS_N - 1) atomicOr(flags, 2u);
    }
}

// ---------------------------------------------------------------- IoU mask rows (f64, verified r2 fixpoint)
__global__ __launch_bounds__(256) void iou_mask(
    const double* __restrict__ selbox, u32* __restrict__ mask)
{
    int b = blockIdx.y, rg = blockIdx.x, t = threadIdx.x;
    int r  = rg * 64 + (t >> 2);
    int w0 = (t & 3) * 16;
    double4 bi = *(const double4*)&selbox[((size_t)b * 2048 + r) * 4];
    double ai = (bi.z - bi.x) * (bi.w - bi.y);
    for (int w = w0; w < w0 + 16; ++w) {
        u32 bits = 0;
        for (int bb = 0; bb < 32; ++bb) {
            int j = w * 32 + bb;
            double4 bj = *(const double4*)&selbox[((size_t)b * 2048 + j) * 4];
            double aj = (bj.z - bj.x) * (bj.w - bj.y);
            double lx = fmax(bi.x, bj.x), ly = fmax(bi.y, bj.y);
            double rx = fmin(bi.z, bj.z), ry = fmin(bi.w, bj.w);
            double iw = fmax(rx - lx, 0.0), ih = fmax(ry - ly, 0.0);
            double inter = iw * ih;
            double iou = inter / (ai + aj - inter + 1e-9);
            bits |= (u32)((iou > 0.7) && (j > r)) << bb;
        }
        mask[((size_t)b * 2048 + r) * 64 + w] = bits;
    }
}

// ---------------------------------------------------------------- wave bit-scan NMS (verified r2 fixpoint)
#define NMS_STEP(i, row) { \
    u32 wv = (u32)__shfl((int)rem, (i) >> 5, 64); \
    u32 alive = ((wv >> ((i) & 31)) & 1u) ^ 1u; \
    rem |= (alive ? (row) : 0u); }

__global__ __launch_bounds__(64) void nms_scan(
    const u32* __restrict__ mask, const u32* __restrict__ selvl, u32* __restrict__ kept)
{
    int b = blockIdx.x, lane = threadIdx.x;
    u32 rem = 0;
    for (int bb = 0; bb < 32; ++bb) {
        int e = lane * 32 + bb;
        u32 s = 1u;
        if (e < PRENMS_N) s = selvl[b * 2048 + e] ? 0u : 1u;
        rem |= s << bb;
    }
    const u32* mrow = mask + (size_t)b * 2048 * 64;
    u32 f0 = mrow[0 * 64 + lane], f1 = mrow[1 * 64 + lane], f2 = mrow[2 * 64 + lane], f3 = mrow[3 * 64 + lane];
    u32 f4 = mrow[4 * 64 + lane], f5 = mrow[5 * 64 + lane], f6 = mrow[6 * 64 + lane], f7 = mrow[7 * 64 + lane];
    for (int i0 = 0; i0 < PRENMS_N; i0 += 8) {
        int nb = i0 + 8;
        u32 n0 = mrow[min(nb + 0, 1999) * 64 + lane];
        u32 n1 = mrow[min(nb + 1, 1999) * 64 + lane];
        u32 n2 = mrow[min(nb + 2, 1999) * 64 + lane];
        u32 n3 = mrow[min(nb + 3, 1999) * 64 + lane];
        u32 n4 = mrow[min(nb + 4, 1999) * 64 + lane];
        u32 n5 = mrow[min(nb + 5, 1999) * 64 + lane];
        u32 n6 = mrow[min(nb + 6, 1999) * 64 + lane];
        u32 n7 = mrow[min(nb + 7, 1999) * 64 + lane];
        NMS_STEP(i0 + 0, f0); NMS_STEP(i0 + 1, f1); NMS_STEP(i0 + 2, f2); NMS_STEP(i0 + 3, f3);
        NMS_STEP(i0 + 4, f4); NMS_STEP(i0 + 5, f5); NMS_STEP(i0 + 6, f6); NMS_STEP(i0 + 7, f7);
        f0 = n0; f1 = n1; f2 = n2; f3 = n3; f4 = n4; f5 = n5; f6 = n6; f7 = n7;
    }
    for (int bb = 0; bb < 32; ++bb) {
        int e = lane * 32 + bb;
        kept[b * 2048 + e] = (e < PRENMS_N && !((rem >> bb) & 1u)) ? 1u : 0u;
    }
}

// ---------------------------------------------------------------- finalize (verified)
__global__ __launch_bounds__(256) void finalize_brute(
    const u32* __restrict__ kept, const u64* __restrict__ selkey, const u32* __restrict__ selidx,
    const double* __restrict__ boxes, float* __restrict__ out)
{
    __shared__ u16 rowOf[PRENMS_N];
    __shared__ u32 nkS;
    int b = blockIdx.x, t = threadIdx.x;
    if (t == 0) {
        int nk = 0;
        for (int e = 0; e < PRENMS_N; ++e)
            rowOf[e] = kept[b * 2048 + e] ? (u16)(nk++) : (u16)0xFFFF;
        nkS = (u32)nk;
        int pos = nk;
        for (int e = 0; e < PRENMS_N; ++e)
            if (rowOf[e] == 0xFFFF) rowOf[e] = (u16)(pos++);
    }
    __syncthreads();
    u32 nk = nkS;
    for (int e = t; e < PRENMS_N; e += 256) {
        u32 r = rowOf[e];
        if (r < TOPK_N) {
            u32 idx = selidx[b * 2048 + e];
            double4 bx = *(const double4*)&boxes[((size_t)b * NANCH + idx) * 4];
            float4 fo = make_float4((float)bx.x, (float)bx.y, (float)bx.z, (float)bx.w);
            *(float4*)&out[((size_t)b * TOPK_N + r) * 4] = fo;
            float sc = (r < nk) ? __uint_as_float((u32)(selkey[b * 2048 + e] >> 32)) : -1.0f;
            out[(size_t)NIMG * TOPK_N * 4 + b * TOPK_N + r] = sc;
        }
    }
}

// ---------------------------------------------------------------- flood tripwire
__global__ void flood_cond(const u32* __restrict__ flags, float* __restrict__ out, u32 hostbits)
{
    u32 f = hostbits ? (8u + hostbits) : (flags ? *flags : 0u);
    if (f == 0u) return;
    float c = 4000.f + 500.f * (float)f;
    int i = blockIdx.x * 256 + threadIdx.x;
    if (i < NIMG * TOPK_N * 5) out[i] = c;
}

// ================================================================ launch
extern "C" void kernel_launch(void* const* d_in, const int* in_sizes, int n_in,
                              void* d_out, int out_size, void* d_ws, size_t ws_size,
                              hipStream_t stream)
{
    float* out = (float*)d_out;
    char* ws = (char*)d_ws;

    const float *feat = nullptr, *conv_w = nullptr, *conv_b = nullptr;
    const float *cls_w = nullptr, *cls_b = nullptr, *box_w = nullptr, *box_b = nullptr;
    const int* shapes = nullptr;
    for (int i = 0; i < n_in; ++i) {
        switch (in_sizes[i]) {
            case 5120000:  feat   = (const float*)d_in[i]; break;
            case 4:        shapes = (const int*)d_in[i]; break;
            case 589824:   conv_w = (const float*)d_in[i]; break;
            case 256:      conv_b = (const float*)d_in[i]; break;
            case 2304:     cls_w  = (const float*)d_in[i]; break;
            case 9:        cls_b  = (const float*)d_in[i]; break;
            case 9216:     box_w  = (const float*)d_in[i]; break;
            case 36:       box_b  = (const float*)d_in[i]; break;
            default: break;
        }
    }
    u32 hostbits = 0;
    if (!feat || !shapes || !conv_w || !conv_b || !cls_w || !cls_b || !box_w || !box_b)
        hostbits |= 2u;

    size_t off = 0;
    auto take = [&](size_t bytes) { size_t o = off; off += (bytes + 255) & ~(size_t)255; return o; };
    size_t off_wt     = take((size_t)2304 * 256 * 4);
    size_t off_wh     = take((size_t)256 * 48 * 4);
    size_t off_hb     = take(256);
    size_t off_logit  = take((size_t)NIMG * NANCH * 8);
    size_t off_delta  = take((size_t)NIMG * NANCH * 4 * 8);
    size_t off_boxes  = take((size_t)NIMG * NANCH * 4 * 8);
    size_t off_valid  = take((size_t)NIMG * NANCH * 4);
    size_t off_km     = take((size_t)NIMG * NANCH * 8);
    size_t off_hist1  = take((size_t)NIMG * 65536 * 4);
    size_t off_hist2  = take((size_t)NIMG * 65536 * 4);
    size_t off_scal   = take(256);
    size_t off_ck     = take((size_t)NIMG * CAND_CAP * 8);
    size_t off_selbox = take((size_t)NIMG * 2048 * 4 * 8);
    size_t off_selvl  = take((size_t)NIMG * 2048 * 4);
    size_t off_selkey = take((size_t)NIMG * 2048 * 8);
    size_t off_selidx = take((size_t)NIMG * 2048 * 4);
    size_t off_mask   = take((size_t)NIMG * 2048 * 64 * 4);
    size_t off_kept   = take((size_t)NIMG * 2048 * 4);
    if (ws_size < off) hostbits |= 1u;

    float*  wt     = (float*) (ws + off_wt);
    float*  wh     = (float*) (ws + off_wh);
    float*  hb     = (float*) (ws + off_hb);
    double* logit  = (double*)(ws + off_logit);
    double* delta  = (double*)(ws + off_delta);
    double* boxes  = (double*)(ws + off_boxes);
    u32*    validf = (u32*)   (ws + off_valid);
    u64*    km     = (u64*)   (ws + off_km);
    u32*    hist1  = (u32*)   (ws + off_hist1);
    u32*    hist2  = (u32*)   (ws + off_hist2);
    u32*    scal   = (u32*)   (ws + off_scal);
    u64*    ck     = (u64*)   (ws + off_ck);
    double* selbox = (double*)(ws + off_selbox);
    u32*    selvl  = (u32*)   (ws + off_selvl);
    u64*    selkey = (u64*)   (ws + off_selkey);
    u32*    selidx = (u32*)   (ws + off_selidx);
    u32*    mask   = (u32*)   (ws + off_mask);
    u32*    kept   = (u32*)   (ws + off_kept);
    u32*    flags  = scal + 32;

    if (hostbits != 0) {
        flood_cond<<<40, 256, 0, stream>>>(nullptr, out, hostbits);
        return;
    }

    // zero hist1+hist2+scal (contiguous)
    hipMemsetAsync(ws + off_hist1, 0, off_ck - off_hist1, stream);

    prep_weights<<<(2304 * 256 + 256 * 48 + 48 + 255) / 256, 256, 0, stream>>>(
        conv_w, cls_w, box_w, cls_b, box_b, wt, wh, hb);

    conv_heads<<<dim3((PIX + TP - 1) / TP, NIMG), 256, 0, stream>>>(
        feat, wt, conv_b, wh, hb, logit, delta);

    decode_anchors<<<(NIMG * NANCH + 255) / 256, 256, 0, stream>>>(
        logit, delta, shapes, boxes, validf, km, hist1);

    scan_hist<<<NIMG, 1024, 0, stream>>>(hist1, scal, 1);
    build_hist2<<<(NIMG * NANCH + 255) / 256, 256, 0, stream>>>(km, scal, hist2);
    scan_hist<<<NIMG, 1024, 0, stream>>>(hist2, scal, 2);
    compact_cand<<<(NIMG * NANCH + 255) / 256, 256, 0, stream>>>(km, scal, ck);

    sort_select<<<NIMG, 1024, 0, stream>>>(ck, scal, boxes, validf,
                                           selbox, selvl, selkey, selidx);

    count_sel<<<(NIMG * NANCH + 255) / 256, 256, 0, stream>>>(km, selkey, scal);
    verify_sel<<<NIMG, 256, 0, stream>>>(selkey, scal, flags);

    iou_mask<<<dim3(32, NIMG), 256, 0, stream>>>(selbox, mask);
    nms_scan<<<NIMG, 64, 0, stream>>>(mask, selvl, kept);

    finalize_brute<<<NIMG, 256, 0, stream>>>(kept, selkey, selidx, boxes, out);

    flood_cond<<<40, 256, 0, stream>>>(flags, out, 0u);
}

// Round 14
// 1731.675 us; speedup vs baseline: 15.4999x; 1.5078x over previous
//
#include <hip/hip_runtime.h>
#include <hip/hip_bf16.h>

typedef unsigned int u32;
typedef unsigned long long u64;
typedef unsigned short u16;

#define NIMG 2
#define CCH 256
#define PIX 10000
#define NANCH 90000
#define PRENMS_N 2000
#define TOPK_N 1000
#define CAND_CAP 4096
#define BBOX_CLIP_D 4.1351665567423558145
#define TP 24
#define BK 32

// ---------------------------------------------------------------- prep weights
__global__ void prep_weights(const float* __restrict__ conv_w,
                             const float* __restrict__ cls_w, const float* __restrict__ box_w,
                             const float* __restrict__ cls_b, const float* __restrict__ box_b,
                             float* __restrict__ wt, float* __restrict__ wh, float* __restrict__ hb)
{
    int i = blockIdx.x * 256 + threadIdx.x;
    if (i < 2304 * 256) {
        int oc = i & 255;
        int k  = i >> 8;
        int ci = k & 255, kid = k >> 8;
        wt[i] = conv_w[(oc * 256 + ci) * 9 + kid];
    }
    int j = i - 2304 * 256;
    if (j >= 0 && j < 256 * 48) {
        int oc = j % 48, c = j / 48;
        float v = 0.f;
        if (oc < 9) v = cls_w[oc * 256 + c];
        else if (oc < 45) v = box_w[(oc - 9) * 256 + c];
        wh[j] = v;
    }
    int h = i - (2304 * 256 + 256 * 48);
    if (h >= 0 && h < 48) {
        float v = 0.f;
        if (h < 9) v = cls_b[h];
        else if (h < 45) v = box_b[h - 9];
        hb[h] = v;
    }
}

// ---------------------------------------------------------------- fused conv3x3+relu+heads (f64)
// Re-mapped: 256 thr = 4 px-groups x 64 oc-quads; 6px x 4oc per thread.
// Accumulation per output is bit-identical to r12/r13: one fma per kg, ascending kg.
struct ConvStage { double As[BK][TP]; float Bs[BK][256]; };   // 6 KB + 32 KB
union ShBuf { ConvStage cv; double Ls[TP][258]; };            // 49.5 KB

__global__ __launch_bounds__(256) void conv_heads(
    const float* __restrict__ feat, const float* __restrict__ wt, const float* __restrict__ conv_b,
    const float* __restrict__ wh, const float* __restrict__ hb,
    double* __restrict__ logits, double* __restrict__ deltas)
{
    __shared__ ShBuf u;
    const int t   = threadIdx.x;
    const int pxg = t >> 6;          // 0..3 -> pixels pxg*6..pxg*6+5
    const int oc0 = (t & 63) * 4;    // 4 output channels
    const int p0  = blockIdx.x * TP;
    const int b   = blockIdx.y;
    double acc[6][4] = {};

    for (int k0 = 0; k0 < 2304; k0 += BK) {
        // stage As (identical math to verified r13 staging)
#pragma unroll
        for (int r = 0; r < 3; ++r) {
            int e  = t + 256 * r;              // < 768 = 32*24
            int kk = e / TP, px = e - kk * TP;
            int kg = k0 + kk;
            int ci = kg & 255, kid = kg >> 8;
            int ky = (kid >= 6) ? 2 : (kid >= 3 ? 1 : 0);
            int kx = kid - ky * 3;
            int p = p0 + px;
            float v = 0.f;
            if (p < PIX) {
                int y = p / 100, x = p - y * 100;
                int iy = y + ky - 1, ix = x + kx - 1;
                if ((u32)iy < 100u && (u32)ix < 100u)
                    v = feat[((size_t)(b * CCH + ci) * 100 + iy) * 100 + ix];
            }
            u.cv.As[kk][px] = (double)v;
        }
        // stage Bs via float4 (same values, vectorized)
#pragma unroll
        for (int r = 0; r < 8; ++r) {
            int e  = t + 256 * r;              // 0..2047 float4 slots
            int kk = e >> 6, oc = (e & 63) * 4;
            *(float4*)&u.cv.Bs[kk][oc] = *(const float4*)&wt[(size_t)(k0 + kk) * 256 + oc];
        }
        __syncthreads();
        for (int kk = 0; kk < BK; ++kk) {
            double2 a01 = *(const double2*)&u.cv.As[kk][pxg * 6 + 0];
            double2 a23 = *(const double2*)&u.cv.As[kk][pxg * 6 + 2];
            double2 a45 = *(const double2*)&u.cv.As[kk][pxg * 6 + 4];
            float4 bq = *(const float4*)&u.cv.Bs[kk][oc0];
            double b0 = (double)bq.x, b1 = (double)bq.y, b2 = (double)bq.z, b3 = (double)bq.w;
            double a0 = a01.x, a1 = a01.y, a2 = a23.x, a3 = a23.y, a4 = a45.x, a5 = a45.y;
            acc[0][0] += a0 * b0; acc[0][1] += a0 * b1; acc[0][2] += a0 * b2; acc[0][3] += a0 * b3;
            acc[1][0] += a1 * b0; acc[1][1] += a1 * b1; acc[1][2] += a1 * b2; acc[1][3] += a1 * b3;
            acc[2][0] += a2 * b0; acc[2][1] += a2 * b1; acc[2][2] += a2 * b2; acc[2][3] += a2 * b3;
            acc[3][0] += a3 * b0; acc[3][1] += a3 * b1; acc[3][2] += a3 * b2; acc[3][3] += a3 * b3;
            acc[4][0] += a4 * b0; acc[4][1] += a4 * b1; acc[4][2] += a4 * b2; acc[4][3] += a4 * b3;
            acc[5][0] += a5 * b0; acc[5][1] += a5 * b1; acc[5][2] += a5 * b2; acc[5][3] += a5 * b3;
        }
        __syncthreads();
    }
    // bias + relu -> Ls[px][oc] (same ops/values as r13 epilogue)
#pragma unroll
    for (int i = 0; i < 6; ++i) {
        int px = pxg * 6 + i;
#pragma unroll
        for (int j = 0; j < 4; ++j)
            u.Ls[px][oc0 + j] = fmax(acc[i][j] + (double)conv_b[oc0 + j], 0.0);
    }
    __syncthreads();
    // heads — unchanged (verified)
    if (t < TP * 8) {
        int px = t >> 3, j = t & 7;
        int p = p0 + px;
        if (p < PIX) {
            for (int k = 0; k < 6; ++k) {
                int oc = j + 8 * k;
                double s = (double)hb[oc];
                for (int c = 0; c < 256; ++c)
                    s += u.Ls[px][c] * (double)wh[c * 48 + oc];
                if (oc < 9)
                    logits[(size_t)b * NANCH + p * 9 + oc] = s;
                else if (oc < 45)
                    deltas[(size_t)b * NANCH * 4 + p * 36 + (oc - 9)] = s;
            }
        }
    }
}

// ---------------------------------------------------------------- decode [verified numerics] + hist1
__global__ void decode_anchors(
    const double* __restrict__ logits, const double* __restrict__ deltas,
    const int* __restrict__ shapes,
    double* __restrict__ boxes, u32* __restrict__ validf, u64* __restrict__ km,
    u32* __restrict__ hist1)
{
    int gid = blockIdx.x * 256 + threadIdx.x;
    if (gid >= NIMG * NANCH) return;
    int b = gid / NANCH, idx = gid - b * NANCH;
    int p = idx / 9, a = idx - p * 9;
    int y = p / 100, x = p - y * 100;
    int si = a % 3, ri = a / 3;
    double scale = (si == 0) ? 128.0 : ((si == 1) ? 256.0 : 512.0);
    double ratio = (ri == 0) ? 0.5 : ((ri == 1) ? 1.0 : 2.0);
    double hr = sqrt(ratio), wr = 1.0 / hr;
    double wsv = wr * scale, hsv = hr * scale;
    double sx = x * 16.0, sy = y * 16.0;
    double ax1 = sx + rint(-wsv * 0.5), ay1 = sy + rint(-hsv * 0.5);
    double ax2 = sx + rint(wsv * 0.5),  ay2 = sy + rint(hsv * 0.5);
    double wa = ax2 - ax1, ha = ay2 - ay1;
    double cxa = ax1 + 0.5 * wa, cya = ay1 + 0.5 * ha;
    double4 d = *(const double4*)&deltas[((size_t)b * NANCH + idx) * 4];
    float dxf = (float)d.x, dyf = (float)d.y;
    float dwf = fminf((float)d.z, (float)BBOX_CLIP_D);
    float dhf = fminf((float)d.w, (float)BBOX_CLIP_D);
    double cx = (double)dxf * wa + cxa, cy = (double)dyf * ha + cya;
    double w = exp((double)dwf) * wa, h = exp((double)dhf) * ha;
    double x1 = cx - 0.5 * w, y1 = cy - 0.5 * h, x2 = cx + 0.5 * w, y2 = cy + 0.5 * h;
    double him = (double)shapes[b * 2 + 0], wim = (double)shapes[b * 2 + 1];
    x1 = fmin(fmax(x1, 0.0), wim); y1 = fmin(fmax(y1, 0.0), him);
    x2 = fmin(fmax(x2, 0.0), wim); y2 = fmin(fmax(y2, 0.0), him);
    u32 valid = ((x2 - x1 >= 16.0) && (y2 - y1 >= 16.0)) ? 1u : 0u;
    float l32 = (float)logits[(size_t)b * NANCH + idx];
    float e32 = (float)exp(-(double)l32);
    float den = 1.0f + e32;
    float s32 = 1.0f / den;
    u32 kh = __float_as_uint(s32);
    double4 bx; bx.x = x1; bx.y = y1; bx.z = x2; bx.w = y2;
    *(double4*)&boxes[((size_t)b * NANCH + idx) * 4] = bx;
    validf[gid] = valid;
    km[gid] = ((u64)kh << 32) | (u32)(~(u32)idx);
    atomicAdd(&hist1[b * 65536 + (kh >> 16)], 1u);
}

// ---------------------------------------------------------------- two-level radix threshold
__global__ __launch_bounds__(1024) void scan_hist(const u32* __restrict__ hist, u32* scal, int level)
{
    __shared__ u32 part[1024];
    int b = blockIdx.x, t = threadIdx.x;
    const u32* h = hist + b * 65536;
    u32 s = 0;
    for (int c = 0; c < 64; ++c) s += h[t * 64 + c];
    part[t] = s; __syncthreads();
    for (int d = 1; d < 1024; d <<= 1) {
        u32 v = part[t] + ((t + d < 1024) ? part[t + d] : 0u);
        __syncthreads(); part[t] = v; __syncthreads();
    }
    u32 base  = (level == 1) ? 0u : scal[2 + b];
    u32 sfx1  = (t < 1023) ? part[t + 1] : 0u;
    u32 above = base + sfx1;
    u32 mine  = part[t] - sfx1;
    if (above < PRENMS_N && above + mine >= PRENMS_N) {
        u32 cum = above;
        for (int c = 63; c >= 0; --c) {
            u32 hv = h[t * 64 + c];
            if (cum + hv >= PRENMS_N) {
                int bin = t * 64 + c;
                if (level == 1) { scal[0 + b] = (u32)bin; scal[2 + b] = cum; }
                else            { scal[4 + b] = (scal[0 + b] << 16) | (u32)bin; scal[6 + b] = cum; }
                break;
            }
            cum += hv;
        }
    }
}

__global__ void build_hist2(const u64* __restrict__ km, const u32* __restrict__ scal,
                            u32* __restrict__ hist2)
{
    int gid = blockIdx.x * 256 + threadIdx.x;
    if (gid >= NIMG * NANCH) return;
    int b = gid / NANCH;
    u32 kh = (u32)(km[gid] >> 32);
    if ((kh >> 16) == scal[0 + b])
        atomicAdd(&hist2[b * 65536 + (kh & 0xFFFFu)], 1u);
}

__global__ void compact_cand(const u64* __restrict__ km, u32* scal, u64* __restrict__ ck)
{
    int gid = blockIdx.x * 256 + threadIdx.x;
    if (gid >= NIMG * NANCH) return;
    int b = gid / NANCH;
    u64 key = km[gid];
    u32 kh = (u32)(key >> 32);
    if (kh >= scal[4 + b]) {
        u32 pos = atomicAdd(&scal[8 + b], 1u);
        if (pos < CAND_CAP) ck[(size_t)b * CAND_CAP + pos] = key;
    }
}

// ---------------------------------------------------------------- bitonic sort 4096 + select
__global__ __launch_bounds__(1024) void sort_select(
    const u64* __restrict__ ck, const u32* __restrict__ scal,
    const double* __restrict__ boxes, const u32* __restrict__ validf,
    double* __restrict__ selbox, u32* __restrict__ selvl,
    u64* __restrict__ selkey, u32* __restrict__ selidx)
{
    __shared__ u64 sk[4096];
    int b = blockIdx.x, t = threadIdx.x;
    u32 n = scal[8 + b]; if (n > CAND_CAP) n = CAND_CAP;
    for (int i = t; i < 4096; i += 1024)
        sk[i] = (i < (int)n) ? ck[(size_t)b * CAND_CAP + i] : 0ull;
    __syncthreads();
    for (int k = 2; k <= 4096; k <<= 1) {
        for (int j = k >> 1; j > 0; j >>= 1) {
            for (int u2 = t; u2 < 2048; u2 += 1024) {
                int i  = (u2 / j) * (2 * j) + (u2 % j);
                int p2 = i + j;
                bool up = ((i & k) == 0);
                u64 ka = sk[i], kc = sk[p2];
                bool sw = up ? (kc > ka) : (ka > kc);
                if (sw) { sk[i] = kc; sk[p2] = ka; }
            }
            __syncthreads();
        }
    }
    for (int e = t; e < PRENMS_N; e += 1024) {
        u64 key = sk[e];
        u32 idx = ~(u32)key;
        selkey[b * 2048 + e] = key;
        u32 g = (idx >= NANCH) ? 0u : idx;
        selidx[b * 2048 + e] = g;
        double4 bx = *(const double4*)&boxes[((size_t)b * NANCH + g) * 4];
        *(double4*)&selbox[((size_t)b * 2048 + e) * 4] = bx;
        selvl[b * 2048 + e] = (idx >= NANCH) ? 0u : validf[(size_t)b * NANCH + g];
    }
    for (int e = PRENMS_N + t; e < 2048; e += 1024) {
        double4 z; z.x = 0.0; z.y = 0.0; z.z = 0.0; z.w = 0.0;
        *(double4*)&selbox[((size_t)b * 2048 + e) * 4] = z;
        selvl[b * 2048 + e] = 0u;
        selkey[b * 2048 + e] = 0ull;
        selidx[b * 2048 + e] = 0u;
    }
}

// ---------------------------------------------------------------- selection certificates (tripwire)
__global__ void count_sel(const u64* __restrict__ km, const u64* __restrict__ selkey, u32* scal)
{
    int gid = blockIdx.x * 256 + threadIdx.x;
    if (gid >= NIMG * NANCH) return;
    int b = gid / NANCH;
    if (km[gid] > selkey[b * 2048 + 1999]) atomicAdd(&scal[12 + b], 1u);
}

__global__ __launch_bounds__(256) void verify_sel(const u64* __restrict__ selkey,
                                                  const u32* __restrict__ scal, u32* flags)
{
    int b = blockIdx.x, t = threadIdx.x;
    for (int e = t; e < PRENMS_N - 1; e += 256)
        if (!(selkey[b * 2048 + e] > selkey[b * 2048 + e + 1])) atomicOr(flags, 4u);
    if (t == 0) {
        u32 n = scal[8 + b];
        if (n < PRENMS_N || n > CAND_CAP) atomicOr(flags, 1u);
        if (scal[12 + b] != PRENMS_N - 1) atomicOr(flags, 2u);
    }
}

// ---------------------------------------------------------------- IoU mask rows (f64)
__global__ __launch_bounds__(256) void iou_mask(
    const double* __restrict__ selbox, u32* __restrict__ mask)
{
    int b = blockIdx.y, rg = blockIdx.x, t = threadIdx.x;
    int r  = rg * 64 + (t >> 2);
    int w0 = (t & 3) * 16;
    double4 bi = *(const double4*)&selbox[((size_t)b * 2048 + r) * 4];
    double ai = (bi.z - bi.x) * (bi.w - bi.y);
    for (int w = w0; w < w0 + 16; ++w) {
        u32 bits = 0;
        for (int bb = 0; bb < 32; ++bb) {
            int j = w * 32 + bb;
            double4 bj = *(const double4*)&selbox[((size_t)b * 2048 + j) * 4];
            double aj = (bj.z - bj.x) * (bj.w - bj.y);
            double lx = fmax(bi.x, bj.x), ly = fmax(bi.y, bj.y);
            double rx = fmin(bi.z, bj.z), ry = fmin(bi.w, bj.w);
            double iw = fmax(rx - lx, 0.0), ih = fmax(ry - ly, 0.0);
            double inter = iw * ih;
            double iou = inter / (ai + aj - inter + 1e-9);
            bits |= (u32)((iou > 0.7) && (j > r)) << bb;
        }
        mask[((size_t)b * 2048 + r) * 64 + w] = bits;
    }
}

// ---------------------------------------------------------------- wave bit-scan NMS (verified fixpoint)
#define NMS_STEP(i, row) { \
    u32 wv = (u32)__shfl((int)rem, (i) >> 5, 64); \
    u32 alive = ((wv >> ((i) & 31)) & 1u) ^ 1u; \
    rem |= (alive ? (row) : 0u); }

__global__ __launch_bounds__(64) void nms_scan(
    const u32* __restrict__ mask, const u32* __restrict__ selvl, u32* __restrict__ kept)
{
    int b = blockIdx.x, lane = threadIdx.x;
    u32 rem = 0;
    for (int bb = 0; bb < 32; ++bb) {
        int e = lane * 32 + bb;
        u32 s = 1u;
        if (e < PRENMS_N) s = selvl[b * 2048 + e] ? 0u : 1u;
        rem |= s << bb;
    }
    const u32* mrow = mask + (size_t)b * 2048 * 64;
    u32 f0 = mrow[0 * 64 + lane], f1 = mrow[1 * 64 + lane], f2 = mrow[2 * 64 + lane], f3 = mrow[3 * 64 + lane];
    u32 f4 = mrow[4 * 64 + lane], f5 = mrow[5 * 64 + lane], f6 = mrow[6 * 64 + lane], f7 = mrow[7 * 64 + lane];
    for (int i0 = 0; i0 < PRENMS_N; i0 += 8) {
        int nb = i0 + 8;
        u32 n0 = mrow[min(nb + 0, 1999) * 64 + lane];
        u32 n1 = mrow[min(nb + 1, 1999) * 64 + lane];
        u32 n2 = mrow[min(nb + 2, 1999) * 64 + lane];
        u32 n3 = mrow[min(nb + 3, 1999) * 64 + lane];
        u32 n4 = mrow[min(nb + 4, 1999) * 64 + lane];
        u32 n5 = mrow[min(nb + 5, 1999) * 64 + lane];
        u32 n6 = mrow[min(nb + 6, 1999) * 64 + lane];
        u32 n7 = mrow[min(nb + 7, 1999) * 64 + lane];
        NMS_STEP(i0 + 0, f0); NMS_STEP(i0 + 1, f1); NMS_STEP(i0 + 2, f2); NMS_STEP(i0 + 3, f3);
        NMS_STEP(i0 + 4, f4); NMS_STEP(i0 + 5, f5); NMS_STEP(i0 + 6, f6); NMS_STEP(i0 + 7, f7);
        f0 = n0; f1 = n1; f2 = n2; f3 = n3; f4 = n4; f5 = n5; f6 = n6; f7 = n7;
    }
    for (int bb = 0; bb < 32; ++bb) {
        int e = lane * 32 + bb;
        kept[b * 2048 + e] = (e < PRENMS_N && !((rem >> bb) & 1u)) ? 1u : 0u;
    }
}

// ---------------------------------------------------------------- finalize (verified)
__global__ __launch_bounds__(256) void finalize_brute(
    const u32* __restrict__ kept, const u64* __restrict__ selkey, const u32* __restrict__ selidx,
    const double* __restrict__ boxes, float* __restrict__ out)
{
    __shared__ u16 rowOf[PRENMS_N];
    __shared__ u32 nkS;
    int b = blockIdx.x, t = threadIdx.x;
    if (t == 0) {
        int nk = 0;
        for (int e = 0; e < PRENMS_N; ++e)
            rowOf[e] = kept[b * 2048 + e] ? (u16)(nk++) : (u16)0xFFFF;
        nkS = (u32)nk;
        int pos = nk;
        for (int e = 0; e < PRENMS_N; ++e)
            if (rowOf[e] == 0xFFFF) rowOf[e] = (u16)(pos++);
    }
    __syncthreads();
    u32 nk = nkS;
    for (int e = t; e < PRENMS_N; e += 256) {
        u32 r = rowOf[e];
        if (r < TOPK_N) {
            u32 idx = selidx[b * 2048 + e];
            double4 bx = *(const double4*)&boxes[((size_t)b * NANCH + idx) * 4];
            float4 fo = make_float4((float)bx.x, (float)bx.y, (float)bx.z, (float)bx.w);
            *(float4*)&out[((size_t)b * TOPK_N + r) * 4] = fo;
            float sc = (r < nk) ? __uint_as_float((u32)(selkey[b * 2048 + e] >> 32)) : -1.0f;
            out[(size_t)NIMG * TOPK_N * 4 + b * TOPK_N + r] = sc;
        }
    }
}

// ---------------------------------------------------------------- flood tripwire
__global__ void flood_cond(const u32* __restrict__ flags, float* __restrict__ out, u32 hostbits)
{
    u32 f = hostbits ? (8u + hostbits) : (flags ? *flags : 0u);
    if (f == 0u) return;
    float c = 4000.f + 500.f * (float)f;
    int i = blockIdx.x * 256 + threadIdx.x;
    if (i < NIMG * TOPK_N * 5) out[i] = c;
}

// ================================================================ launch
extern "C" void kernel_launch(void* const* d_in, const int* in_sizes, int n_in,
                              void* d_out, int out_size, void* d_ws, size_t ws_size,
                              hipStream_t stream)
{
    float* out = (float*)d_out;
    char* ws = (char*)d_ws;

    const float *feat = nullptr, *conv_w = nullptr, *conv_b = nullptr;
    const float *cls_w = nullptr, *cls_b = nullptr, *box_w = nullptr, *box_b = nullptr;
    const int* shapes = nullptr;
    for (int i = 0; i < n_in; ++i) {
        switch (in_sizes[i]) {
            case 5120000:  feat   = (const float*)d_in[i]; break;
            case 4:        shapes = (const int*)d_in[i]; break;
            case 589824:   conv_w = (const float*)d_in[i]; break;
            case 256:      conv_b = (const float*)d_in[i]; break;
            case 2304:     cls_w  = (const float*)d_in[i]; break;
            case 9:        cls_b  = (const float*)d_in[i]; break;
            case 9216:     box_w  = (const float*)d_in[i]; break;
            case 36:       box_b  = (const float*)d_in[i]; break;
            default: break;
        }
    }
    u32 hostbits = 0;
    if (!feat || !shapes || !conv_w || !conv_b || !cls_w || !cls_b || !box_w || !box_b)
        hostbits |= 2u;

    size_t off = 0;
    auto take = [&](size_t bytes) { size_t o = off; off += (bytes + 255) & ~(size_t)255; return o; };
    size_t off_wt     = take((size_t)2304 * 256 * 4);
    size_t off_wh     = take((size_t)256 * 48 * 4);
    size_t off_hb     = take(256);
    size_t off_logit  = take((size_t)NIMG * NANCH * 8);
    size_t off_delta  = take((size_t)NIMG * NANCH * 4 * 8);
    size_t off_boxes  = take((size_t)NIMG * NANCH * 4 * 8);
    size_t off_valid  = take((size_t)NIMG * NANCH * 4);
    size_t off_km     = take((size_t)NIMG * NANCH * 8);
    size_t off_hist1  = take((size_t)NIMG * 65536 * 4);
    size_t off_hist2  = take((size_t)NIMG * 65536 * 4);
    size_t off_scal   = take(256);
    size_t off_ck     = take((size_t)NIMG * CAND_CAP * 8);
    size_t off_selbox = take((size_t)NIMG * 2048 * 4 * 8);
    size_t off_selvl  = take((size_t)NIMG * 2048 * 4);
    size_t off_selkey = take((size_t)NIMG * 2048 * 8);
    size_t off_selidx = take((size_t)NIMG * 2048 * 4);
    size_t off_mask   = take((size_t)NIMG * 2048 * 64 * 4);
    size_t off_kept   = take((size_t)NIMG * 2048 * 4);
    if (ws_size < off) hostbits |= 1u;

    float*  wt     = (float*) (ws + off_wt);
    float*  wh     = (float*) (ws + off_wh);
    float*  hb     = (float*) (ws + off_hb);
    double* logit  = (double*)(ws + off_logit);
    double* delta  = (double*)(ws + off_delta);
    double* boxes  = (double*)(ws + off_boxes);
    u32*    validf = (u32*)   (ws + off_valid);
    u64*    km     = (u64*)   (ws + off_km);
    u32*    hist1  = (u32*)   (ws + off_hist1);
    u32*    hist2  = (u32*)   (ws + off_hist2);
    u32*    scal   = (u32*)   (ws + off_scal);
    u64*    ck     = (u64*)   (ws + off_ck);
    double* selbox = (double*)(ws + off_selbox);
    u32*    selvl  = (u32*)   (ws + off_selvl);
    u64*    selkey = (u64*)   (ws + off_selkey);
    u32*    selidx = (u32*)   (ws + off_selidx);
    u32*    mask   = (u32*)   (ws + off_mask);
    u32*    kept   = (u32*)   (ws + off_kept);
    u32*    flags  = scal + 32;

    if (hostbits != 0) {
        flood_cond<<<40, 256, 0, stream>>>(nullptr, out, hostbits);
        return;
    }

    hipMemsetAsync(ws + off_hist1, 0, off_ck - off_hist1, stream);

    prep_weights<<<(2304 * 256 + 256 * 48 + 48 + 255) / 256, 256, 0, stream>>>(
        conv_w, cls_w, box_w, cls_b, box_b, wt, wh, hb);

    conv_heads<<<dim3((PIX + TP - 1) / TP, NIMG), 256, 0, stream>>>(
        feat, wt, conv_b, wh, hb, logit, delta);

    decode_anchors<<<(NIMG * NANCH + 255) / 256, 256, 0, stream>>>(
        logit, delta, shapes, boxes, validf, km, hist1);

    scan_hist<<<NIMG, 1024, 0, stream>>>(hist1, scal, 1);
    build_hist2<<<(NIMG * NANCH + 255) / 256, 256, 0, stream>>>(km, scal, hist2);
    scan_hist<<<NIMG, 1024, 0, stream>>>(hist2, scal, 2);
    compact_cand<<<(NIMG * NANCH + 255) / 256, 256, 0, stream>>>(km, scal, ck);

    sort_select<<<NIMG, 1024, 0, stream>>>(ck, scal, boxes, validf,
                                           selbox, selvl, selkey, selidx);

    count_sel<<<(NIMG * NANCH + 255) / 256, 256, 0, stream>>>(km, selkey, scal);
    verify_sel<<<NIMG, 256, 0, stream>>>(selkey, scal, flags);

    iou_mask<<<dim3(32, NIMG), 256, 0, stream>>>(selbox, mask);
    nms_scan<<<NIMG, 64, 0, stream>>>(mask, selvl, kept);

    finalize_brute<<<NIMG, 256, 0, stream>>>(kept, selkey, selidx, boxes, out);

    flood_cond<<<40, 256, 0, stream>>>(flags, out, 0u);
}

// Round 15
// 1664.790 us; speedup vs baseline: 16.1226x; 1.0402x over previous
//
#include <hip/hip_runtime.h>
#include <hip/hip_bf16.h>

typedef unsigned int u32;
typedef unsigned long long u64;
typedef unsigned short u16;

#define NIMG 2
#define CCH 256
#define PIX 10000
#define NANCH 90000
#define PRENMS_N 2000
#define TOPK_N 1000
#define CAND_CAP 4096
#define BBOX_CLIP_D 4.1351665567423558145
#define TP 32
#define BK 32
#define HPX 16

// ---------------------------------------------------------------- prep weights
__global__ void prep_weights(const float* __restrict__ conv_w,
                             const float* __restrict__ cls_w, const float* __restrict__ box_w,
                             const float* __restrict__ cls_b, const float* __restrict__ box_b,
                             float* __restrict__ wt, float* __restrict__ wh, float* __restrict__ hb)
{
    int i = blockIdx.x * 256 + threadIdx.x;
    if (i < 2304 * 256) {
        int oc = i & 255;
        int k  = i >> 8;
        int ci = k & 255, kid = k >> 8;
        wt[i] = conv_w[(oc * 256 + ci) * 9 + kid];
    }
    int j = i - 2304 * 256;
    if (j >= 0 && j < 256 * 48) {
        int oc = j % 48, c = j / 48;
        float v = 0.f;
        if (oc < 9) v = cls_w[oc * 256 + c];
        else if (oc < 45) v = box_w[(oc - 9) * 256 + c];
        wh[j] = v;
    }
    int h = i - (2304 * 256 + 256 * 48);
    if (h >= 0 && h < 48) {
        float v = 0.f;
        if (h < 9) v = cls_b[h];
        else if (h < 45) v = box_b[h - 9];
        hb[h] = v;
    }
}

// ---------------------------------------------------------------- conv3x3+relu (f64) -> rpn global
// 256 thr = 4 px-groups x 64 oc-quads; 8 px x 4 oc per thread.
// Per-output accumulation: one fma per kg, ascending kg (bit-exact vs r12-r14).
__global__ __launch_bounds__(256) void conv3x3(
    const float* __restrict__ feat, const float* __restrict__ wt, const float* __restrict__ conv_b,
    double* __restrict__ rpn)
{
    __shared__ double As[BK][TP];      // 8 KB
    __shared__ float  Bs[BK][256];     // 32 KB  (total 40960 B -> 4 blocks/CU)
    const int t   = threadIdx.x;
    const int pxg = t >> 6;            // 0..3 -> pixels pxg*8..pxg*8+7
    const int oc0 = (t & 63) * 4;
    const int p0  = blockIdx.x * TP;
    const int b   = blockIdx.y;
    double acc[8][4] = {};

    for (int k0 = 0; k0 < 2304; k0 += BK) {
#pragma unroll
        for (int r = 0; r < 4; ++r) {
            int e  = t + 256 * r;          // 0..1023 = 32*32
            int kk = e >> 5, px = e & 31;
            int kg = k0 + kk;
            int ci = kg & 255, kid = kg >> 8;
            int ky = (kid >= 6) ? 2 : (kid >= 3 ? 1 : 0);
            int kx = kid - ky * 3;
            int p = p0 + px;
            float v = 0.f;
            if (p < PIX) {
                int y = p / 100, x = p - y * 100;
                int iy = y + ky - 1, ix = x + kx - 1;
                if ((u32)iy < 100u && (u32)ix < 100u)
                    v = feat[((size_t)(b * CCH + ci) * 100 + iy) * 100 + ix];
            }
            As[kk][px] = (double)v;
        }
#pragma unroll
        for (int r = 0; r < 8; ++r) {
            int e  = t + 256 * r;
            int kk = e >> 6, oc = (e & 63) * 4;
            *(float4*)&Bs[kk][oc] = *(const float4*)&wt[(size_t)(k0 + kk) * 256 + oc];
        }
        __syncthreads();
        for (int kk = 0; kk < BK; ++kk) {
            double2 a01 = *(const double2*)&As[kk][pxg * 8 + 0];
            double2 a23 = *(const double2*)&As[kk][pxg * 8 + 2];
            double2 a45 = *(const double2*)&As[kk][pxg * 8 + 4];
            double2 a67 = *(const double2*)&As[kk][pxg * 8 + 6];
            float4 bq = *(const float4*)&Bs[kk][oc0];
            double b0 = (double)bq.x, b1 = (double)bq.y, b2 = (double)bq.z, b3 = (double)bq.w;
            double a0 = a01.x, a1 = a01.y, a2 = a23.x, a3 = a23.y;
            double a4 = a45.x, a5 = a45.y, a6 = a67.x, a7 = a67.y;
            acc[0][0] += a0 * b0; acc[0][1] += a0 * b1; acc[0][2] += a0 * b2; acc[0][3] += a0 * b3;
            acc[1][0] += a1 * b0; acc[1][1] += a1 * b1; acc[1][2] += a1 * b2; acc[1][3] += a1 * b3;
            acc[2][0] += a2 * b0; acc[2][1] += a2 * b1; acc[2][2] += a2 * b2; acc[2][3] += a2 * b3;
            acc[3][0] += a3 * b0; acc[3][1] += a3 * b1; acc[3][2] += a3 * b2; acc[3][3] += a3 * b3;
            acc[4][0] += a4 * b0; acc[4][1] += a4 * b1; acc[4][2] += a4 * b2; acc[4][3] += a4 * b3;
            acc[5][0] += a5 * b0; acc[5][1] += a5 * b1; acc[5][2] += a5 * b2; acc[5][3] += a5 * b3;
            acc[6][0] += a6 * b0; acc[6][1] += a6 * b1; acc[6][2] += a6 * b2; acc[6][3] += a6 * b3;
            acc[7][0] += a7 * b0; acc[7][1] += a7 * b1; acc[7][2] += a7 * b2; acc[7][3] += a7 * b3;
        }
        __syncthreads();
    }
#pragma unroll
    for (int i = 0; i < 8; ++i) {
        int p = p0 + pxg * 8 + i;
        if (p < PIX) {
            double2 v0, v1;
            v0.x = fmax(acc[i][0] + (double)conv_b[oc0 + 0], 0.0);
            v0.y = fmax(acc[i][1] + (double)conv_b[oc0 + 1], 0.0);
            v1.x = fmax(acc[i][2] + (double)conv_b[oc0 + 2], 0.0);
            v1.y = fmax(acc[i][3] + (double)conv_b[oc0 + 3], 0.0);
            *(double2*)&rpn[((size_t)b * PIX + p) * 256 + oc0 + 0] = v0;
            *(double2*)&rpn[((size_t)b * PIX + p) * 256 + oc0 + 2] = v1;
        }
    }
}

// ---------------------------------------------------------------- heads (f64) — identical accumulation
__global__ __launch_bounds__(128) void heads(
    const double* __restrict__ rpn, const float* __restrict__ wh, const float* __restrict__ hb,
    double* __restrict__ logits, double* __restrict__ deltas)
{
    __shared__ double Ls[HPX][257];    // 32.9 KB, pad -> conflict-free
    const int t  = threadIdx.x;
    const int p0 = blockIdx.x * HPX;
    const int b  = blockIdx.y;
#pragma unroll
    for (int r = 0; r < 32; ++r) {
        int e = t + 128 * r;           // 0..4095 = 16*256
        int pxl = e >> 8, c = e & 255;
        int p = p0 + pxl;
        Ls[pxl][c] = (p < PIX) ? rpn[((size_t)b * PIX + p) * 256 + c] : 0.0;
    }
    __syncthreads();
    int pxl = t >> 3, j = t & 7;
    int p = p0 + pxl;
    if (p < PIX) {
        for (int k = 0; k < 6; ++k) {
            int oc = j + 8 * k;
            double s = (double)hb[oc];
            for (int c = 0; c < 256; ++c)
                s += Ls[pxl][c] * (double)wh[c * 48 + oc];
            if (oc < 9)
                logits[(size_t)b * NANCH + p * 9 + oc] = s;
            else if (oc < 45)
                deltas[(size_t)b * NANCH * 4 + p * 36 + (oc - 9)] = s;
        }
    }
}

// ---------------------------------------------------------------- decode [verified numerics] + hist1
__global__ void decode_anchors(
    const double* __restrict__ logits, const double* __restrict__ deltas,
    const int* __restrict__ shapes,
    double* __restrict__ boxes, u32* __restrict__ validf, u64* __restrict__ km,
    u32* __restrict__ hist1)
{
    int gid = blockIdx.x * 256 + threadIdx.x;
    if (gid >= NIMG * NANCH) return;
    int b = gid / NANCH, idx = gid - b * NANCH;
    int p = idx / 9, a = idx - p * 9;
    int y = p / 100, x = p - y * 100;
    int si = a % 3, ri = a / 3;
    double scale = (si == 0) ? 128.0 : ((si == 1) ? 256.0 : 512.0);
    double ratio = (ri == 0) ? 0.5 : ((ri == 1) ? 1.0 : 2.0);
    double hr = sqrt(ratio), wr = 1.0 / hr;
    double wsv = wr * scale, hsv = hr * scale;
    double sx = x * 16.0, sy = y * 16.0;
    double ax1 = sx + rint(-wsv * 0.5), ay1 = sy + rint(-hsv * 0.5);
    double ax2 = sx + rint(wsv * 0.5),  ay2 = sy + rint(hsv * 0.5);
    double wa = ax2 - ax1, ha = ay2 - ay1;
    double cxa = ax1 + 0.5 * wa, cya = ay1 + 0.5 * ha;
    double4 d = *(const double4*)&deltas[((size_t)b * NANCH + idx) * 4];
    float dxf = (float)d.x, dyf = (float)d.y;
    float dwf = fminf((float)d.z, (float)BBOX_CLIP_D);
    float dhf = fminf((float)d.w, (float)BBOX_CLIP_D);
    double cx = (double)dxf * wa + cxa, cy = (double)dyf * ha + cya;
    double w = exp((double)dwf) * wa, h = exp((double)dhf) * ha;
    double x1 = cx - 0.5 * w, y1 = cy - 0.5 * h, x2 = cx + 0.5 * w, y2 = cy + 0.5 * h;
    double him = (double)shapes[b * 2 + 0], wim = (double)shapes[b * 2 + 1];
    x1 = fmin(fmax(x1, 0.0), wim); y1 = fmin(fmax(y1, 0.0), him);
    x2 = fmin(fmax(x2, 0.0), wim); y2 = fmin(fmax(y2, 0.0), him);
    u32 valid = ((x2 - x1 >= 16.0) && (y2 - y1 >= 16.0)) ? 1u : 0u;
    float l32 = (float)logits[(size_t)b * NANCH + idx];
    float e32 = (float)exp(-(double)l32);
    float den = 1.0f + e32;
    float s32 = 1.0f / den;
    u32 kh = __float_as_uint(s32);
    double4 bx; bx.x = x1; bx.y = y1; bx.z = x2; bx.w = y2;
    *(double4*)&boxes[((size_t)b * NANCH + idx) * 4] = bx;
    validf[gid] = valid;
    km[gid] = ((u64)kh << 32) | (u32)(~(u32)idx);
    atomicAdd(&hist1[b * 65536 + (kh >> 16)], 1u);
}

// ---------------------------------------------------------------- two-level radix threshold
__global__ __launch_bounds__(1024) void scan_hist(const u32* __restrict__ hist, u32* scal, int level)
{
    __shared__ u32 part[1024];
    int b = blockIdx.x, t = threadIdx.x;
    const u32* h = hist + b * 65536;
    u32 s = 0;
    for (int c = 0; c < 64; ++c) s += h[t * 64 + c];
    part[t] = s; __syncthreads();
    for (int d = 1; d < 1024; d <<= 1) {
        u32 v = part[t] + ((t + d < 1024) ? part[t + d] : 0u);
        __syncthreads(); part[t] = v; __syncthreads();
    }
    u32 base  = (level == 1) ? 0u : scal[2 + b];
    u32 sfx1  = (t < 1023) ? part[t + 1] : 0u;
    u32 above = base + sfx1;
    u32 mine  = part[t] - sfx1;
    if (above < PRENMS_N && above + mine >= PRENMS_N) {
        u32 cum = above;
        for (int c = 63; c >= 0; --c) {
            u32 hv = h[t * 64 + c];
            if (cum + hv >= PRENMS_N) {
                int bin = t * 64 + c;
                if (level == 1) { scal[0 + b] = (u32)bin; scal[2 + b] = cum; }
                else            { scal[4 + b] = (scal[0 + b] << 16) | (u32)bin; scal[6 + b] = cum; }
                break;
            }
            cum += hv;
        }
    }
}

__global__ void build_hist2(const u64* __restrict__ km, const u32* __restrict__ scal,
                            u32* __restrict__ hist2)
{
    int gid = blockIdx.x * 256 + threadIdx.x;
    if (gid >= NIMG * NANCH) return;
    int b = gid / NANCH;
    u32 kh = (u32)(km[gid] >> 32);
    if ((kh >> 16) == scal[0 + b])
        atomicAdd(&hist2[b * 65536 + (kh & 0xFFFFu)], 1u);
}

__global__ void compact_cand(const u64* __restrict__ km, u32* scal, u64* __restrict__ ck)
{
    int gid = blockIdx.x * 256 + threadIdx.x;
    if (gid >= NIMG * NANCH) return;
    int b = gid / NANCH;
    u64 key = km[gid];
    u32 kh = (u32)(key >> 32);
    if (kh >= scal[4 + b]) {
        u32 pos = atomicAdd(&scal[8 + b], 1u);
        if (pos < CAND_CAP) ck[(size_t)b * CAND_CAP + pos] = key;
    }
}

// ---------------------------------------------------------------- bitonic sort 4096 + select
__global__ __launch_bounds__(1024) void sort_select(
    const u64* __restrict__ ck, const u32* __restrict__ scal,
    const double* __restrict__ boxes, const u32* __restrict__ validf,
    double* __restrict__ selbox, u32* __restrict__ selvl,
    u64* __restrict__ selkey, u32* __restrict__ selidx)
{
    __shared__ u64 sk[4096];
    int b = blockIdx.x, t = threadIdx.x;
    u32 n = scal[8 + b]; if (n > CAND_CAP) n = CAND_CAP;
    for (int i = t; i < 4096; i += 1024)
        sk[i] = (i < (int)n) ? ck[(size_t)b * CAND_CAP + i] : 0ull;
    __syncthreads();
    for (int k = 2; k <= 4096; k <<= 1) {
        for (int j = k >> 1; j > 0; j >>= 1) {
            for (int u2 = t; u2 < 2048; u2 += 1024) {
                int i  = (u2 / j) * (2 * j) + (u2 % j);
                int p2 = i + j;
                bool up = ((i & k) == 0);
                u64 ka = sk[i], kc = sk[p2];
                bool sw = up ? (kc > ka) : (ka > kc);
                if (sw) { sk[i] = kc; sk[p2] = ka; }
            }
            __syncthreads();
        }
    }
    for (int e = t; e < PRENMS_N; e += 1024) {
        u64 key = sk[e];
        u32 idx = ~(u32)key;
        selkey[b * 2048 + e] = key;
        u32 g = (idx >= NANCH) ? 0u : idx;
        selidx[b * 2048 + e] = g;
        double4 bx = *(const double4*)&boxes[((size_t)b * NANCH + g) * 4];
        *(double4*)&selbox[((size_t)b * 2048 + e) * 4] = bx;
        selvl[b * 2048 + e] = (idx >= NANCH) ? 0u : validf[(size_t)b * NANCH + g];
    }
    for (int e = PRENMS_N + t; e < 2048; e += 1024) {
        double4 z; z.x = 0.0; z.y = 0.0; z.z = 0.0; z.w = 0.0;
        *(double4*)&selbox[((size_t)b * 2048 + e) * 4] = z;
        selvl[b * 2048 + e] = 0u;
        selkey[b * 2048 + e] = 0ull;
        selidx[b * 2048 + e] = 0u;
    }
}

// ---------------------------------------------------------------- selection certificates (tripwire)
__global__ void count_sel(const u64* __restrict__ km, const u64* __restrict__ selkey, u32* scal)
{
    int gid = blockIdx.x * 256 + threadIdx.x;
    if (gid >= NIMG * NANCH) return;
    int b = gid / NANCH;
    if (km[gid] > selkey[b * 2048 + 1999]) atomicAdd(&scal[12 + b], 1u);
}

__global__ __launch_bounds__(256) void verify_sel(const u64* __restrict__ selkey,
                                                  const u32* __restrict__ scal, u32* flags)
{
    int b = blockIdx.x, t = threadIdx.x;
    for (int e = t; e < PRENMS_N - 1; e += 256)
        if (!(selkey[b * 2048 + e] > selkey[b * 2048 + e + 1])) atomicOr(flags, 4u);
    if (t == 0) {
        u32 n = scal[8 + b];
        if (n < PRENMS_N || n > CAND_CAP) atomicOr(flags, 1u);
        if (scal[12 + b] != PRENMS_N - 1) atomicOr(flags, 2u);
    }
}

// ---------------------------------------------------------------- IoU mask rows (f64)
__global__ __launch_bounds__(256) void iou_mask(
    const double* __restrict__ selbox, u32* __restrict__ mask)
{
    int b = blockIdx.y, rg = blockIdx.x, t = threadIdx.x;
    int r  = rg * 64 + (t >> 2);
    int w0 = (t & 3) * 16;
    double4 bi = *(const double4*)&selbox[((size_t)b * 2048 + r) * 4];
    double ai = (bi.z - bi.x) * (bi.w - bi.y);
    for (int w = w0; w < w0 + 16; ++w) {
        u32 bits = 0;
        for (int bb = 0; bb < 32; ++bb) {
            int j = w * 32 + bb;
            double4 bj = *(const double4*)&selbox[((size_t)b * 2048 + j) * 4];
            double aj = (bj.z - bj.x) * (bj.w - bj.y);
            double lx = fmax(bi.x, bj.x), ly = fmax(bi.y, bj.y);
            double rx = fmin(bi.z, bj.z), ry = fmin(bi.w, bj.w);
            double iw = fmax(rx - lx, 0.0), ih = fmax(ry - ly, 0.0);
            double inter = iw * ih;
            double iou = inter / (ai + aj - inter + 1e-9);
            bits |= (u32)((iou > 0.7) && (j > r)) << bb;
        }
        mask[((size_t)b * 2048 + r) * 64 + w] = bits;
    }
}

// ---------------------------------------------------------------- wave bit-scan NMS (verified fixpoint)
#define NMS_STEP(i, row) { \
    u32 wv = (u32)__shfl((int)rem, (i) >> 5, 64); \
    u32 alive = ((wv >> ((i) & 31)) & 1u) ^ 1u; \
    rem |= (alive ? (row) : 0u); }

__global__ __launch_bounds__(64) void nms_scan(
    const u32* __restrict__ mask, const u32* __restrict__ selvl, u32* __restrict__ kept)
{
    int b = blockIdx.x, lane = threadIdx.x;
    u32 rem = 0;
    for (int bb = 0; bb < 32; ++bb) {
        int e = lane * 32 + bb;
        u32 s = 1u;
        if (e < PRENMS_N) s = selvl[b * 2048 + e] ? 0u : 1u;
        rem |= s << bb;
    }
    const u32* mrow = mask + (size_t)b * 2048 * 64;
    u32 f0 = mrow[0 * 64 + lane], f1 = mrow[1 * 64 + lane], f2 = mrow[2 * 64 + lane], f3 = mrow[3 * 64 + lane];
    u32 f4 = mrow[4 * 64 + lane], f5 = mrow[5 * 64 + lane], f6 = mrow[6 * 64 + lane], f7 = mrow[7 * 64 + lane];
    for (int i0 = 0; i0 < PRENMS_N; i0 += 8) {
        int nb = i0 + 8;
        u32 n0 = mrow[min(nb + 0, 1999) * 64 + lane];
        u32 n1 = mrow[min(nb + 1, 1999) * 64 + lane];
        u32 n2 = mrow[min(nb + 2, 1999) * 64 + lane];
        u32 n3 = mrow[min(nb + 3, 1999) * 64 + lane];
        u32 n4 = mrow[min(nb + 4, 1999) * 64 + lane];
        u32 n5 = mrow[min(nb + 5, 1999) * 64 + lane];
        u32 n6 = mrow[min(nb + 6, 1999) * 64 + lane];
        u32 n7 = mrow[min(nb + 7, 1999) * 64 + lane];
        NMS_STEP(i0 + 0, f0); NMS_STEP(i0 + 1, f1); NMS_STEP(i0 + 2, f2); NMS_STEP(i0 + 3, f3);
        NMS_STEP(i0 + 4, f4); NMS_STEP(i0 + 5, f5); NMS_STEP(i0 + 6, f6); NMS_STEP(i0 + 7, f7);
        f0 = n0; f1 = n1; f2 = n2; f3 = n3; f4 = n4; f5 = n5; f6 = n6; f7 = n7;
    }
    for (int bb = 0; bb < 32; ++bb) {
        int e = lane * 32 + bb;
        kept[b * 2048 + e] = (e < PRENMS_N && !((rem >> bb) & 1u)) ? 1u : 0u;
    }
}

// ---------------------------------------------------------------- finalize (verified)
__global__ __launch_bounds__(256) void finalize_brute(
    const u32* __restrict__ kept, const u64* __restrict__ selkey, const u32* __restrict__ selidx,
    const double* __restrict__ boxes, float* __restrict__ out)
{
    __shared__ u16 rowOf[PRENMS_N];
    __shared__ u32 nkS;
    int b = blockIdx.x, t = threadIdx.x;
    if (t == 0) {
        int nk = 0;
        for (int e = 0; e < PRENMS_N; ++e)
            rowOf[e] = kept[b * 2048 + e] ? (u16)(nk++) : (u16)0xFFFF;
        nkS = (u32)nk;
        int pos = nk;
        for (int e = 0; e < PRENMS_N; ++e)
            if (rowOf[e] == 0xFFFF) rowOf[e] = (u16)(pos++);
    }
    __syncthreads();
    u32 nk = nkS;
    for (int e = t; e < PRENMS_N; e += 256) {
        u32 r = rowOf[e];
        if (r < TOPK_N) {
            u32 idx = selidx[b * 2048 + e];
            double4 bx = *(const double4*)&boxes[((size_t)b * NANCH + idx) * 4];
            float4 fo = make_float4((float)bx.x, (float)bx.y, (float)bx.z, (float)bx.w);
            *(float4*)&out[((size_t)b * TOPK_N + r) * 4] = fo;
            float sc = (r < nk) ? __uint_as_float((u32)(selkey[b * 2048 + e] >> 32)) : -1.0f;
            out[(size_t)NIMG * TOPK_N * 4 + b * TOPK_N + r] = sc;
        }
    }
}

// ---------------------------------------------------------------- flood tripwire
__global__ void flood_cond(const u32* __restrict__ flags, float* __restrict__ out, u32 hostbits)
{
    u32 f = hostbits ? (8u + hostbits) : (flags ? *flags : 0u);
    if (f == 0u) return;
    float c = 4000.f + 500.f * (float)f;
    int i = blockIdx.x * 256 + threadIdx.x;
    if (i < NIMG * TOPK_N * 5) out[i] = c;
}

// ================================================================ launch
extern "C" void kernel_launch(void* const* d_in, const int* in_sizes, int n_in,
                              void* d_out, int out_size, void* d_ws, size_t ws_size,
                              hipStream_t stream)
{
    float* out = (float*)d_out;
    char* ws = (char*)d_ws;

    const float *feat = nullptr, *conv_w = nullptr, *conv_b = nullptr;
    const float *cls_w = nullptr, *cls_b = nullptr, *box_w = nullptr, *box_b = nullptr;
    const int* shapes = nullptr;
    for (int i = 0; i < n_in; ++i) {
        switch (in_sizes[i]) {
            case 5120000:  feat   = (const float*)d_in[i]; break;
            case 4:        shapes = (const int*)d_in[i]; break;
            case 589824:   conv_w = (const float*)d_in[i]; break;
            case 256:      conv_b = (const float*)d_in[i]; break;
            case 2304:     cls_w  = (const float*)d_in[i]; break;
            case 9:        cls_b  = (const float*)d_in[i]; break;
            case 9216:     box_w  = (const float*)d_in[i]; break;
            case 36:       box_b  = (const float*)d_in[i]; break;
            default: break;
        }
    }
    u32 hostbits = 0;
    if (!feat || !shapes || !conv_w || !conv_b || !cls_w || !cls_b || !box_w || !box_b)
        hostbits |= 2u;

    size_t off = 0;
    auto take = [&](size_t bytes) { size_t o = off; off += (bytes + 255) & ~(size_t)255; return o; };
    size_t off_wt     = take((size_t)2304 * 256 * 4);
    size_t off_wh     = take((size_t)256 * 48 * 4);
    size_t off_hb     = take(256);
    size_t off_rpn    = take((size_t)NIMG * PIX * 256 * 8);   // 41 MB f64
    size_t off_logit  = take((size_t)NIMG * NANCH * 8);
    size_t off_delta  = take((size_t)NIMG * NANCH * 4 * 8);
    size_t off_boxes  = take((size_t)NIMG * NANCH * 4 * 8);
    size_t off_valid  = take((size_t)NIMG * NANCH * 4);
    size_t off_km     = take((size_t)NIMG * NANCH * 8);
    size_t off_hist1  = take((size_t)NIMG * 65536 * 4);
    size_t off_hist2  = take((size_t)NIMG * 65536 * 4);
    size_t off_scal   = take(256);
    size_t off_ck     = take((size_t)NIMG * CAND_CAP * 8);
    size_t off_selbox = take((size_t)NIMG * 2048 * 4 * 8);
    size_t off_selvl  = take((size_t)NIMG * 2048 * 4);
    size_t off_selkey = take((size_t)NIMG * 2048 * 8);
    size_t off_selidx = take((size_t)NIMG * 2048 * 4);
    size_t off_mask   = take((size_t)NIMG * 2048 * 64 * 4);
    size_t off_kept   = take((size_t)NIMG * 2048 * 4);
    if (ws_size < off) hostbits |= 1u;

    float*  wt     = (float*) (ws + off_wt);
    float*  wh     = (float*) (ws + off_wh);
    float*  hb     = (float*) (ws + off_hb);
    double* rpn    = (double*)(ws + off_rpn);
    double* logit  = (double*)(ws + off_logit);
    double* delta  = (double*)(ws + off_delta);
    double* boxes  = (double*)(ws + off_boxes);
    u32*    validf = (u32*)   (ws + off_valid);
    u64*    km     = (u64*)   (ws + off_km);
    u32*    hist1  = (u32*)   (ws + off_hist1);
    u32*    hist2  = (u32*)   (ws + off_hist2);
    u32*    scal   = (u32*)   (ws + off_scal);
    u64*    ck     = (u64*)   (ws + off_ck);
    double* selbox = (double*)(ws + off_selbox);
    u32*    selvl  = (u32*)   (ws + off_selvl);
    u64*    selkey = (u64*)   (ws + off_selkey);
    u32*    selidx = (u32*)   (ws + off_selidx);
    u32*    mask   = (u32*)   (ws + off_mask);
    u32*    kept   = (u32*)   (ws + off_kept);
    u32*    flags  = scal + 32;

    if (hostbits != 0) {
        flood_cond<<<40, 256, 0, stream>>>(nullptr, out, hostbits);
        return;
    }

    hipMemsetAsync(ws + off_hist1, 0, off_ck - off_hist1, stream);

    prep_weights<<<(2304 * 256 + 256 * 48 + 48 + 255) / 256, 256, 0, stream>>>(
        conv_w, cls_w, box_w, cls_b, box_b, wt, wh, hb);

    conv3x3<<<dim3((PIX + TP - 1) / TP, NIMG), 256, 0, stream>>>(feat, wt, conv_b, rpn);

    heads<<<dim3((PIX + HPX - 1) / HPX, NIMG), 128, 0, stream>>>(rpn, wh, hb, logit, delta);

    decode_anchors<<<(NIMG * NANCH + 255) / 256, 256, 0, stream>>>(
        logit, delta, shapes, boxes, validf, km, hist1);

    scan_hist<<<NIMG, 1024, 0, stream>>>(hist1, scal, 1);
    build_hist2<<<(NIMG * NANCH + 255) / 256, 256, 0, stream>>>(km, scal, hist2);
    scan_hist<<<NIMG, 1024, 0, stream>>>(hist2, scal, 2);
    compact_cand<<<(NIMG * NANCH + 255) / 256, 256, 0, stream>>>(km, scal, ck);

    sort_select<<<NIMG, 1024, 0, stream>>>(ck, scal, boxes, validf,
                                           selbox, selvl, selkey, selidx);

    count_sel<<<(NIMG * NANCH + 255) / 256, 256, 0, stream>>>(km, selkey, scal);
    verify_sel<<<NIMG, 256, 0, stream>>>(selkey, scal, flags);

    iou_mask<<<dim3(32, NIMG), 256, 0, stream>>>(selbox, mask);
    nms_scan<<<NIMG, 64, 0, stream>>>(mask, selvl, kept);

    finalize_brute<<<NIMG, 256, 0, stream>>>(kept, selkey, selidx, boxes, out);

    flood_cond<<<40, 256, 0, stream>>>(flags, out, 0u);
}

// Round 16
// 1561.658 us; speedup vs baseline: 17.1873x; 1.0660x over previous
//
#include <hip/hip_runtime.h>
#include <hip/hip_bf16.h>

typedef unsigned int u32;
typedef unsigned long long u64;
typedef unsigned short u16;

#define NIMG 2
#define CCH 256
#define PIX 10000
#define NANCH 90000
#define PRENMS_N 2000
#define TOPK_N 1000
#define CAND_CAP 4096
#define BBOX_CLIP_D 4.1351665567423558145
#define TP 32
#define BK 32
#define HPX 16

// ---------------------------------------------------------------- prep weights
__global__ void prep_weights(const float* __restrict__ conv_w,
                             const float* __restrict__ cls_w, const float* __restrict__ box_w,
                             const float* __restrict__ cls_b, const float* __restrict__ box_b,
                             float* __restrict__ wt, float* __restrict__ wh, float* __restrict__ hb)
{
    int i = blockIdx.x * 256 + threadIdx.x;
    if (i < 2304 * 256) {
        int oc = i & 255;
        int k  = i >> 8;
        int ci = k & 255, kid = k >> 8;
        wt[i] = conv_w[(oc * 256 + ci) * 9 + kid];
    }
    int j = i - 2304 * 256;
    if (j >= 0 && j < 256 * 48) {
        int oc = j % 48, c = j / 48;
        float v = 0.f;
        if (oc < 9) v = cls_w[oc * 256 + c];
        else if (oc < 45) v = box_w[(oc - 9) * 256 + c];
        wh[j] = v;
    }
    int h = i - (2304 * 256 + 256 * 48);
    if (h >= 0 && h < 48) {
        float v = 0.f;
        if (h < 9) v = cls_b[h];
        else if (h < 45) v = box_b[h - 9];
        hb[h] = v;
    }
}

// ---------------------------------------------------------------- conv3x3+relu (f64) -> rpn global
// 512 thr = 8 px-groups x 64 oc-quads; 4 px x 4 oc per thread.
// Per-output accumulation: one fma per kg, ascending kg (bit-exact vs r12-r15).
__global__ __launch_bounds__(512) void conv3x3(
    const float* __restrict__ feat, const float* __restrict__ wt, const float* __restrict__ conv_b,
    double* __restrict__ rpn)
{
    __shared__ double As[BK][TP];      // 8 KB
    __shared__ float  Bs[BK][256];     // 32 KB  (total 40960 B -> 4 blocks/CU)
    const int t   = threadIdx.x;
    const int pxg = t >> 6;            // 0..7 -> pixels pxg*4..pxg*4+3
    const int oc0 = (t & 63) * 4;
    const int p0  = blockIdx.x * TP;
    const int b   = blockIdx.y;
    double acc[4][4] = {};

    for (int k0 = 0; k0 < 2304; k0 += BK) {
#pragma unroll
        for (int r = 0; r < 2; ++r) {
            int e  = t + 512 * r;          // 0..1023 = 32*32
            int kk = e >> 5, px = e & 31;
            int kg = k0 + kk;
            int ci = kg & 255, kid = kg >> 8;
            int ky = (kid >= 6) ? 2 : (kid >= 3 ? 1 : 0);
            int kx = kid - ky * 3;
            int p = p0 + px;
            float v = 0.f;
            if (p < PIX) {
                int y = p / 100, x = p - y * 100;
                int iy = y + ky - 1, ix = x + kx - 1;
                if ((u32)iy < 100u && (u32)ix < 100u)
                    v = feat[((size_t)(b * CCH + ci) * 100 + iy) * 100 + ix];
            }
            As[kk][px] = (double)v;
        }
#pragma unroll
        for (int r = 0; r < 4; ++r) {
            int e  = t + 512 * r;          // 0..2047 float4 slots
            int kk = e >> 6, oc = (e & 63) * 4;
            *(float4*)&Bs[kk][oc] = *(const float4*)&wt[(size_t)(k0 + kk) * 256 + oc];
        }
        __syncthreads();
        for (int kk = 0; kk < BK; ++kk) {
            double2 a01 = *(const double2*)&As[kk][pxg * 4 + 0];
            double2 a23 = *(const double2*)&As[kk][pxg * 4 + 2];
            float4 bq = *(const float4*)&Bs[kk][oc0];
            double b0 = (double)bq.x, b1 = (double)bq.y, b2 = (double)bq.z, b3 = (double)bq.w;
            double a0 = a01.x, a1 = a01.y, a2 = a23.x, a3 = a23.y;
            acc[0][0] += a0 * b0; acc[0][1] += a0 * b1; acc[0][2] += a0 * b2; acc[0][3] += a0 * b3;
            acc[1][0] += a1 * b0; acc[1][1] += a1 * b1; acc[1][2] += a1 * b2; acc[1][3] += a1 * b3;
            acc[2][0] += a2 * b0; acc[2][1] += a2 * b1; acc[2][2] += a2 * b2; acc[2][3] += a2 * b3;
            acc[3][0] += a3 * b0; acc[3][1] += a3 * b1; acc[3][2] += a3 * b2; acc[3][3] += a3 * b3;
        }
        __syncthreads();
    }
#pragma unroll
    for (int i = 0; i < 4; ++i) {
        int p = p0 + pxg * 4 + i;
        if (p < PIX) {
            double2 v0, v1;
            v0.x = fmax(acc[i][0] + (double)conv_b[oc0 + 0], 0.0);
            v0.y = fmax(acc[i][1] + (double)conv_b[oc0 + 1], 0.0);
            v1.x = fmax(acc[i][2] + (double)conv_b[oc0 + 2], 0.0);
            v1.y = fmax(acc[i][3] + (double)conv_b[oc0 + 3], 0.0);
            *(double2*)&rpn[((size_t)b * PIX + p) * 256 + oc0 + 0] = v0;
            *(double2*)&rpn[((size_t)b * PIX + p) * 256 + oc0 + 2] = v1;
        }
    }
}

// ---------------------------------------------------------------- heads (f64) — identical accumulation
__global__ __launch_bounds__(128) void heads(
    const double* __restrict__ rpn, const float* __restrict__ wh, const float* __restrict__ hb,
    double* __restrict__ logits, double* __restrict__ deltas)
{
    __shared__ double Ls[HPX][257];
    const int t  = threadIdx.x;
    const int p0 = blockIdx.x * HPX;
    const int b  = blockIdx.y;
#pragma unroll
    for (int r = 0; r < 32; ++r) {
        int e = t + 128 * r;
        int pxl = e >> 8, c = e & 255;
        int p = p0 + pxl;
        Ls[pxl][c] = (p < PIX) ? rpn[((size_t)b * PIX + p) * 256 + c] : 0.0;
    }
    __syncthreads();
    int pxl = t >> 3, j = t & 7;
    int p = p0 + pxl;
    if (p < PIX) {
        for (int k = 0; k < 6; ++k) {
            int oc = j + 8 * k;
            double s = (double)hb[oc];
            for (int c = 0; c < 256; ++c)
                s += Ls[pxl][c] * (double)wh[c * 48 + oc];
            if (oc < 9)
                logits[(size_t)b * NANCH + p * 9 + oc] = s;
            else if (oc < 45)
                deltas[(size_t)b * NANCH * 4 + p * 36 + (oc - 9)] = s;
        }
    }
}

// ---------------------------------------------------------------- decode [verified numerics] + hist1
__global__ void decode_anchors(
    const double* __restrict__ logits, const double* __restrict__ deltas,
    const int* __restrict__ shapes,
    double* __restrict__ boxes, u32* __restrict__ validf, u64* __restrict__ km,
    u32* __restrict__ hist1)
{
    int gid = blockIdx.x * 256 + threadIdx.x;
    if (gid >= NIMG * NANCH) return;
    int b = gid / NANCH, idx = gid - b * NANCH;
    int p = idx / 9, a = idx - p * 9;
    int y = p / 100, x = p - y * 100;
    int si = a % 3, ri = a / 3;
    double scale = (si == 0) ? 128.0 : ((si == 1) ? 256.0 : 512.0);
    double ratio = (ri == 0) ? 0.5 : ((ri == 1) ? 1.0 : 2.0);
    double hr = sqrt(ratio), wr = 1.0 / hr;
    double wsv = wr * scale, hsv = hr * scale;
    double sx = x * 16.0, sy = y * 16.0;
    double ax1 = sx + rint(-wsv * 0.5), ay1 = sy + rint(-hsv * 0.5);
    double ax2 = sx + rint(wsv * 0.5),  ay2 = sy + rint(hsv * 0.5);
    double wa = ax2 - ax1, ha = ay2 - ay1;
    double cxa = ax1 + 0.5 * wa, cya = ay1 + 0.5 * ha;
    double4 d = *(const double4*)&deltas[((size_t)b * NANCH + idx) * 4];
    float dxf = (float)d.x, dyf = (float)d.y;
    float dwf = fminf((float)d.z, (float)BBOX_CLIP_D);
    float dhf = fminf((float)d.w, (float)BBOX_CLIP_D);
    double cx = (double)dxf * wa + cxa, cy = (double)dyf * ha + cya;
    double w = exp((double)dwf) * wa, h = exp((double)dhf) * ha;
    double x1 = cx - 0.5 * w, y1 = cy - 0.5 * h, x2 = cx + 0.5 * w, y2 = cy + 0.5 * h;
    double him = (double)shapes[b * 2 + 0], wim = (double)shapes[b * 2 + 1];
    x1 = fmin(fmax(x1, 0.0), wim); y1 = fmin(fmax(y1, 0.0), him);
    x2 = fmin(fmax(x2, 0.0), wim); y2 = fmin(fmax(y2, 0.0), him);
    u32 valid = ((x2 - x1 >= 16.0) && (y2 - y1 >= 16.0)) ? 1u : 0u;
    float l32 = (float)logits[(size_t)b * NANCH + idx];
    float e32 = (float)exp(-(double)l32);
    float den = 1.0f + e32;
    float s32 = 1.0f / den;
    u32 kh = __float_as_uint(s32);
    double4 bx; bx.x = x1; bx.y = y1; bx.z = x2; bx.w = y2;
    *(double4*)&boxes[((size_t)b * NANCH + idx) * 4] = bx;
    validf[gid] = valid;
    km[gid] = ((u64)kh << 32) | (u32)(~(u32)idx);
    atomicAdd(&hist1[b * 65536 + (kh >> 16)], 1u);
}

// ---------------------------------------------------------------- two-level radix threshold
__global__ __launch_bounds__(1024) void scan_hist(const u32* __restrict__ hist, u32* scal, int level)
{
    __shared__ u32 part[1024];
    int b = blockIdx.x, t = threadIdx.x;
    const u32* h = hist + b * 65536;
    u32 s = 0;
    for (int c = 0; c < 64; ++c) s += h[t * 64 + c];
    part[t] = s; __syncthreads();
    for (int d = 1; d < 1024; d <<= 1) {
        u32 v = part[t] + ((t + d < 1024) ? part[t + d] : 0u);
        __syncthreads(); part[t] = v; __syncthreads();
    }
    u32 base  = (level == 1) ? 0u : scal[2 + b];
    u32 sfx1  = (t < 1023) ? part[t + 1] : 0u;
    u32 above = base + sfx1;
    u32 mine  = part[t] - sfx1;
    if (above < PRENMS_N && above + mine >= PRENMS_N) {
        u32 cum = above;
        for (int c = 63; c >= 0; --c) {
            u32 hv = h[t * 64 + c];
            if (cum + hv >= PRENMS_N) {
                int bin = t * 64 + c;
                if (level == 1) { scal[0 + b] = (u32)bin; scal[2 + b] = cum; }
                else            { scal[4 + b] = (scal[0 + b] << 16) | (u32)bin; scal[6 + b] = cum; }
                break;
            }
            cum += hv;
        }
    }
}

__global__ void build_hist2(const u64* __restrict__ km, const u32* __restrict__ scal,
                            u32* __restrict__ hist2)
{
    int gid = blockIdx.x * 256 + threadIdx.x;
    if (gid >= NIMG * NANCH) return;
    int b = gid / NANCH;
    u32 kh = (u32)(km[gid] >> 32);
    if ((kh >> 16) == scal[0 + b])
        atomicAdd(&hist2[b * 65536 + (kh & 0xFFFFu)], 1u);
}

__global__ void compact_cand(const u64* __restrict__ km, u32* scal, u64* __restrict__ ck)
{
    int gid = blockIdx.x * 256 + threadIdx.x;
    if (gid >= NIMG * NANCH) return;
    int b = gid / NANCH;
    u64 key = km[gid];
    u32 kh = (u32)(key >> 32);
    if (kh >= scal[4 + b]) {
        u32 pos = atomicAdd(&scal[8 + b], 1u);
        if (pos < CAND_CAP) ck[(size_t)b * CAND_CAP + pos] = key;
    }
}

// ---------------------------------------------------------------- bitonic sort 4096 + select
__global__ __launch_bounds__(1024) void sort_select(
    const u64* __restrict__ ck, const u32* __restrict__ scal,
    const double* __restrict__ boxes, const u32* __restrict__ validf,
    double* __restrict__ selbox, u32* __restrict__ selvl,
    u64* __restrict__ selkey, u32* __restrict__ selidx)
{
    __shared__ u64 sk[4096];
    int b = blockIdx.x, t = threadIdx.x;
    u32 n = scal[8 + b]; if (n > CAND_CAP) n = CAND_CAP;
    for (int i = t; i < 4096; i += 1024)
        sk[i] = (i < (int)n) ? ck[(size_t)b * CAND_CAP + i] : 0ull;
    __syncthreads();
    for (int k = 2; k <= 4096; k <<= 1) {
        for (int j = k >> 1; j > 0; j >>= 1) {
            for (int u2 = t; u2 < 2048; u2 += 1024) {
                int i  = (u2 / j) * (2 * j) + (u2 % j);
                int p2 = i + j;
                bool up = ((i & k) == 0);
                u64 ka = sk[i], kc = sk[p2];
                bool sw = up ? (kc > ka) : (ka > kc);
                if (sw) { sk[i] = kc; sk[p2] = ka; }
            }
            __syncthreads();
        }
    }
    for (int e = t; e < PRENMS_N; e += 1024) {
        u64 key = sk[e];
        u32 idx = ~(u32)key;
        selkey[b * 2048 + e] = key;
        u32 g = (idx >= NANCH) ? 0u : idx;
        selidx[b * 2048 + e] = g;
        double4 bx = *(const double4*)&boxes[((size_t)b * NANCH + g) * 4];
        *(double4*)&selbox[((size_t)b * 2048 + e) * 4] = bx;
        selvl[b * 2048 + e] = (idx >= NANCH) ? 0u : validf[(size_t)b * NANCH + g];
    }
    for (int e = PRENMS_N + t; e < 2048; e += 1024) {
        double4 z; z.x = 0.0; z.y = 0.0; z.z = 0.0; z.w = 0.0;
        *(double4*)&selbox[((size_t)b * 2048 + e) * 4] = z;
        selvl[b * 2048 + e] = 0u;
        selkey[b * 2048 + e] = 0ull;
        selidx[b * 2048 + e] = 0u;
    }
}

// ---------------------------------------------------------------- IoU mask rows (f64)
__global__ __launch_bounds__(256) void iou_mask(
    const double* __restrict__ selbox, u32* __restrict__ mask)
{
    int b = blockIdx.y, rg = blockIdx.x, t = threadIdx.x;
    int r  = rg * 64 + (t >> 2);
    int w0 = (t & 3) * 16;
    double4 bi = *(const double4*)&selbox[((size_t)b * 2048 + r) * 4];
    double ai = (bi.z - bi.x) * (bi.w - bi.y);
    for (int w = w0; w < w0 + 16; ++w) {
        u32 bits = 0;
        for (int bb = 0; bb < 32; ++bb) {
            int j = w * 32 + bb;
            double4 bj = *(const double4*)&selbox[((size_t)b * 2048 + j) * 4];
            double aj = (bj.z - bj.x) * (bj.w - bj.y);
            double lx = fmax(bi.x, bj.x), ly = fmax(bi.y, bj.y);
            double rx = fmin(bi.z, bj.z), ry = fmin(bi.w, bj.w);
            double iw = fmax(rx - lx, 0.0), ih = fmax(ry - ly, 0.0);
            double inter = iw * ih;
            double iou = inter / (ai + aj - inter + 1e-9);
            bits |= (u32)((iou > 0.7) && (j > r)) << bb;
        }
        mask[((size_t)b * 2048 + r) * 64 + w] = bits;
    }
}

// ---------------------------------------------------------------- wave bit-scan NMS (verified fixpoint)
#define NMS_STEP(i, row) { \
    u32 wv = (u32)__shfl((int)rem, (i) >> 5, 64); \
    u32 alive = ((wv >> ((i) & 31)) & 1u) ^ 1u; \
    rem |= (alive ? (row) : 0u); }

__global__ __launch_bounds__(64) void nms_scan(
    const u32* __restrict__ mask, const u32* __restrict__ selvl, u32* __restrict__ kept)
{
    int b = blockIdx.x, lane = threadIdx.x;
    u32 rem = 0;
    for (int bb = 0; bb < 32; ++bb) {
        int e = lane * 32 + bb;
        u32 s = 1u;
        if (e < PRENMS_N) s = selvl[b * 2048 + e] ? 0u : 1u;
        rem |= s << bb;
    }
    const u32* mrow = mask + (size_t)b * 2048 * 64;
    u32 f0 = mrow[0 * 64 + lane], f1 = mrow[1 * 64 + lane], f2 = mrow[2 * 64 + lane], f3 = mrow[3 * 64 + lane];
    u32 f4 = mrow[4 * 64 + lane], f5 = mrow[5 * 64 + lane], f6 = mrow[6 * 64 + lane], f7 = mrow[7 * 64 + lane];
    for (int i0 = 0; i0 < PRENMS_N; i0 += 8) {
        int nb = i0 + 8;
        u32 n0 = mrow[min(nb + 0, 1999) * 64 + lane];
        u32 n1 = mrow[min(nb + 1, 1999) * 64 + lane];
        u32 n2 = mrow[min(nb + 2, 1999) * 64 + lane];
        u32 n3 = mrow[min(nb + 3, 1999) * 64 + lane];
        u32 n4 = mrow[min(nb + 4, 1999) * 64 + lane];
        u32 n5 = mrow[min(nb + 5, 1999) * 64 + lane];
        u32 n6 = mrow[min(nb + 6, 1999) * 64 + lane];
        u32 n7 = mrow[min(nb + 7, 1999) * 64 + lane];
        NMS_STEP(i0 + 0, f0); NMS_STEP(i0 + 1, f1); NMS_STEP(i0 + 2, f2); NMS_STEP(i0 + 3, f3);
        NMS_STEP(i0 + 4, f4); NMS_STEP(i0 + 5, f5); NMS_STEP(i0 + 6, f6); NMS_STEP(i0 + 7, f7);
        f0 = n0; f1 = n1; f2 = n2; f3 = n3; f4 = n4; f5 = n5; f6 = n6; f7 = n7;
    }
    for (int bb = 0; bb < 32; ++bb) {
        int e = lane * 32 + bb;
        kept[b * 2048 + e] = (e < PRENMS_N && !((rem >> bb) & 1u)) ? 1u : 0u;
    }
}

// ---------------------------------------------------------------- finalize (verified)
__global__ __launch_bounds__(256) void finalize_brute(
    const u32* __restrict__ kept, const u64* __restrict__ selkey, const u32* __restrict__ selidx,
    const double* __restrict__ boxes, float* __restrict__ out)
{
    __shared__ u16 rowOf[PRENMS_N];
    __shared__ u32 nkS;
    int b = blockIdx.x, t = threadIdx.x;
    if (t == 0) {
        int nk = 0;
        for (int e = 0; e < PRENMS_N; ++e)
            rowOf[e] = kept[b * 2048 + e] ? (u16)(nk++) : (u16)0xFFFF;
        nkS = (u32)nk;
        int pos = nk;
        for (int e = 0; e < PRENMS_N; ++e)
            if (rowOf[e] == 0xFFFF) rowOf[e] = (u16)(pos++);
    }
    __syncthreads();
    u32 nk = nkS;
    for (int e = t; e < PRENMS_N; e += 256) {
        u32 r = rowOf[e];
        if (r < TOPK_N) {
            u32 idx = selidx[b * 2048 + e];
            double4 bx = *(const double4*)&boxes[((size_t)b * NANCH + idx) * 4];
            float4 fo = make_float4((float)bx.x, (float)bx.y, (float)bx.z, (float)bx.w);
            *(float4*)&out[((size_t)b * TOPK_N + r) * 4] = fo;
            float sc = (r < nk) ? __uint_as_float((u32)(selkey[b * 2048 + e] >> 32)) : -1.0f;
            out[(size_t)NIMG * TOPK_N * 4 + b * TOPK_N + r] = sc;
        }
    }
}

// ---------------------------------------------------------------- host-error flood
__global__ void flood(float* __restrict__ out, u32 hostbits)
{
    if (hostbits == 0u) return;
    int bit = __ffs(hostbits) - 1;
    float c = 60000.f + 4000.f * (float)bit;
    int i = blockIdx.x * 256 + threadIdx.x;
    if (i < NIMG * TOPK_N * 5) out[i] = c;
}

// ================================================================ launch
extern "C" void kernel_launch(void* const* d_in, const int* in_sizes, int n_in,
                              void* d_out, int out_size, void* d_ws, size_t ws_size,
                              hipStream_t stream)
{
    float* out = (float*)d_out;
    char* ws = (char*)d_ws;

    const float *feat = nullptr, *conv_w = nullptr, *conv_b = nullptr;
    const float *cls_w = nullptr, *cls_b = nullptr, *box_w = nullptr, *box_b = nullptr;
    const int* shapes = nullptr;
    for (int i = 0; i < n_in; ++i) {
        switch (in_sizes[i]) {
            case 5120000:  feat   = (const float*)d_in[i]; break;
            case 4:        shapes = (const int*)d_in[i]; break;
            case 589824:   conv_w = (const float*)d_in[i]; break;
            case 256:      conv_b = (const float*)d_in[i]; break;
            case 2304:     cls_w  = (const float*)d_in[i]; break;
            case 9:        cls_b  = (const float*)d_in[i]; break;
            case 9216:     box_w  = (const float*)d_in[i]; break;
            case 36:       box_b  = (const float*)d_in[i]; break;
            default: break;
        }
    }
    u32 hostbits = 0;
    if (!feat || !shapes || !conv_w || !conv_b || !cls_w || !cls_b || !box_w || !box_b)
        hostbits |= 2u;

    size_t off = 0;
    auto take = [&](size_t bytes) { size_t o = off; off += (bytes + 255) & ~(size_t)255; return o; };
    size_t off_wt     = take((size_t)2304 * 256 * 4);
    size_t off_wh     = take((size_t)256 * 48 * 4);
    size_t off_hb     = take(256);
    size_t off_rpn    = take((size_t)NIMG * PIX * 256 * 8);
    size_t off_logit  = take((size_t)NIMG * NANCH * 8);
    size_t off_delta  = take((size_t)NIMG * NANCH * 4 * 8);
    size_t off_boxes  = take((size_t)NIMG * NANCH * 4 * 8);
    size_t off_valid  = take((size_t)NIMG * NANCH * 4);
    size_t off_km     = take((size_t)NIMG * NANCH * 8);
    size_t off_hist1  = take((size_t)NIMG * 65536 * 4);
    size_t off_hist2  = take((size_t)NIMG * 65536 * 4);
    size_t off_scal   = take(256);
    size_t off_ck     = take((size_t)NIMG * CAND_CAP * 8);
    size_t off_selbox = take((size_t)NIMG * 2048 * 4 * 8);
    size_t off_selvl  = take((size_t)NIMG * 2048 * 4);
    size_t off_selkey = take((size_t)NIMG * 2048 * 8);
    size_t off_selidx = take((size_t)NIMG * 2048 * 4);
    size_t off_mask   = take((size_t)NIMG * 2048 * 64 * 4);
    size_t off_kept   = take((size_t)NIMG * 2048 * 4);
    if (ws_size < off) hostbits |= 1u;

    float*  wt     = (float*) (ws + off_wt);
    float*  wh     = (float*) (ws + off_wh);
    float*  hb     = (float*) (ws + off_hb);
    double* rpn    = (double*)(ws + off_rpn);
    double* logit  = (double*)(ws + off_logit);
    double* delta  = (double*)(ws + off_delta);
    double* boxes  = (double*)(ws + off_boxes);
    u32*    validf = (u32*)   (ws + off_valid);
    u64*    km     = (u64*)   (ws + off_km);
    u32*    hist1  = (u32*)   (ws + off_hist1);
    u32*    hist2  = (u32*)   (ws + off_hist2);
    u32*    scal   = (u32*)   (ws + off_scal);
    u64*    ck     = (u64*)   (ws + off_ck);
    double* selbox = (double*)(ws + off_selbox);
    u32*    selvl  = (u32*)   (ws + off_selvl);
    u64*    selkey = (u64*)   (ws + off_selkey);
    u32*    selidx = (u32*)   (ws + off_selidx);
    u32*    mask   = (u32*)   (ws + off_mask);
    u32*    kept   = (u32*)   (ws + off_kept);

    if (hostbits != 0) {
        flood<<<40, 256, 0, stream>>>(out, hostbits);
        return;
    }

    hipMemsetAsync(ws + off_hist1, 0, off_ck - off_hist1, stream);

    prep_weights<<<(2304 * 256 + 256 * 48 + 48 + 255) / 256, 256, 0, stream>>>(
        conv_w, cls_w, box_w, cls_b, box_b, wt, wh, hb);

    conv3x3<<<dim3((PIX + TP - 1) / TP, NIMG), 512, 0, stream>>>(feat, wt, conv_b, rpn);

    heads<<<dim3((PIX + HPX - 1) / HPX, NIMG), 128, 0, stream>>>(rpn, wh, hb, logit, delta);

    decode_anchors<<<(NIMG * NANCH + 255) / 256, 256, 0, stream>>>(
        logit, delta, shapes, boxes, validf, km, hist1);

    scan_hist<<<NIMG, 1024, 0, stream>>>(hist1, scal, 1);
    build_hist2<<<(NIMG * NANCH + 255) / 256, 256, 0, stream>>>(km, scal, hist2);
    scan_hist<<<NIMG, 1024, 0, stream>>>(hist2, scal, 2);
    compact_cand<<<(NIMG * NANCH + 255) / 256, 256, 0, stream>>>(km, scal, ck);

    sort_select<<<NIMG, 1024, 0, stream>>>(ck, scal, boxes, validf,
                                           selbox, selvl, selkey, selidx);

    iou_mask<<<dim3(32, NIMG), 256, 0, stream>>>(selbox, mask);
    nms_scan<<<NIMG, 64, 0, stream>>>(mask, selvl, kept);

    finalize_brute<<<NIMG, 256, 0, stream>>>(kept, selkey, selidx, boxes, out);
}

// Round 17
// 1364.203 us; speedup vs baseline: 19.6750x; 1.1447x over previous
//
#include <hip/hip_runtime.h>
#include <hip/hip_bf16.h>

typedef unsigned int u32;
typedef unsigned long long u64;
typedef unsigned short u16;

#define NIMG 2
#define CCH 256
#define PIX 10000
#define NANCH 90000
#define PRENMS_N 2000
#define TOPK_N 1000
#define CAND_CAP 4096
#define BBOX_CLIP_D 4.1351665567423558145
#define TP 32
#define BK 32
#define OCH 128
#define HPX 16

// ---------------------------------------------------------------- prep weights
__global__ void prep_weights(const float* __restrict__ conv_w,
                             const float* __restrict__ cls_w, const float* __restrict__ box_w,
                             const float* __restrict__ cls_b, const float* __restrict__ box_b,
                             float* __restrict__ wt, float* __restrict__ wh, float* __restrict__ hb)
{
    int i = blockIdx.x * 256 + threadIdx.x;
    if (i < 2304 * 256) {
        int oc = i & 255;
        int k  = i >> 8;
        int ci = k & 255, kid = k >> 8;
        wt[i] = conv_w[(oc * 256 + ci) * 9 + kid];
    }
    int j = i - 2304 * 256;
    if (j >= 0 && j < 256 * 48) {
        int oc = j % 48, c = j / 48;
        float v = 0.f;
        if (oc < 9) v = cls_w[oc * 256 + c];
        else if (oc < 45) v = box_w[(oc - 9) * 256 + c];
        wh[j] = v;
    }
    int h = i - (2304 * 256 + 256 * 48);
    if (h >= 0 && h < 48) {
        float v = 0.f;
        if (h < 9) v = cls_b[h];
        else if (h < 45) v = box_b[h - 9];
        hb[h] = v;
    }
}

// ---------------------------------------------------------------- conv3x3+relu (f64) -> rpn global
// grid (313, ocHalf, img); 256 thr = 8 pxg x 32 ocq; 4 px x 4 oc per thread.
// Per-output accumulation: one fma per kg, ascending kg (bit-exact vs r12-r16).
__global__ __launch_bounds__(256) void conv3x3(
    const float* __restrict__ feat, const float* __restrict__ wt, const float* __restrict__ conv_b,
    double* __restrict__ rpn)
{
    __shared__ double As[BK][TP];      // 8 KB
    __shared__ float  Bs[BK][OCH];     // 16 KB (total 24576 B)
    const int t   = threadIdx.x;
    const int pxg = t >> 5;                          // 0..7 -> pixels pxg*4..pxg*4+3
    const int ocl = (t & 31) * 4;                    // local oc within half
    const int oc0 = blockIdx.y * OCH + ocl;
    const int p0  = blockIdx.x * TP;
    const int b   = blockIdx.z;
    double acc[4][4] = {};

    for (int k0 = 0; k0 < 2304; k0 += BK) {
#pragma unroll
        for (int r = 0; r < 4; ++r) {
            int e  = t + 256 * r;          // 0..1023 = 32*32
            int kk = e >> 5, px = e & 31;
            int kg = k0 + kk;
            int ci = kg & 255, kid = kg >> 8;
            int ky = (kid >= 6) ? 2 : (kid >= 3 ? 1 : 0);
            int kx = kid - ky * 3;
            int p = p0 + px;
            float v = 0.f;
            if (p < PIX) {
                int y = p / 100, x = p - y * 100;
                int iy = y + ky - 1, ix = x + kx - 1;
                if ((u32)iy < 100u && (u32)ix < 100u)
                    v = feat[((size_t)(b * CCH + ci) * 100 + iy) * 100 + ix];
            }
            As[kk][px] = (double)v;
        }
#pragma unroll
        for (int r = 0; r < 4; ++r) {
            int e  = t + 256 * r;          // 0..1023 float4 slots = 32*32
            int kk = e >> 5, oc = (e & 31) * 4;
            *(float4*)&Bs[kk][oc] =
                *(const float4*)&wt[(size_t)(k0 + kk) * 256 + blockIdx.y * OCH + oc];
        }
        __syncthreads();
        for (int kk = 0; kk < BK; ++kk) {
            double2 a01 = *(const double2*)&As[kk][pxg * 4 + 0];
            double2 a23 = *(const double2*)&As[kk][pxg * 4 + 2];
            float4 bq = *(const float4*)&Bs[kk][ocl];
            double b0 = (double)bq.x, b1 = (double)bq.y, b2 = (double)bq.z, b3 = (double)bq.w;
            double a0 = a01.x, a1 = a01.y, a2 = a23.x, a3 = a23.y;
            acc[0][0] += a0 * b0; acc[0][1] += a0 * b1; acc[0][2] += a0 * b2; acc[0][3] += a0 * b3;
            acc[1][0] += a1 * b0; acc[1][1] += a1 * b1; acc[1][2] += a1 * b2; acc[1][3] += a1 * b3;
            acc[2][0] += a2 * b0; acc[2][1] += a2 * b1; acc[2][2] += a2 * b2; acc[2][3] += a2 * b3;
            acc[3][0] += a3 * b0; acc[3][1] += a3 * b1; acc[3][2] += a3 * b2; acc[3][3] += a3 * b3;
        }
        __syncthreads();
    }
#pragma unroll
    for (int i = 0; i < 4; ++i) {
        int p = p0 + pxg * 4 + i;
        if (p < PIX) {
            double2 v0, v1;
            v0.x = fmax(acc[i][0] + (double)conv_b[oc0 + 0], 0.0);
            v0.y = fmax(acc[i][1] + (double)conv_b[oc0 + 1], 0.0);
            v1.x = fmax(acc[i][2] + (double)conv_b[oc0 + 2], 0.0);
            v1.y = fmax(acc[i][3] + (double)conv_b[oc0 + 3], 0.0);
            *(double2*)&rpn[((size_t)b * PIX + p) * 256 + oc0 + 0] = v0;
            *(double2*)&rpn[((size_t)b * PIX + p) * 256 + oc0 + 2] = v1;
        }
    }
}

// ---------------------------------------------------------------- heads (f64) — identical accumulation
__global__ __launch_bounds__(128) void heads(
    const double* __restrict__ rpn, const float* __restrict__ wh, const float* __restrict__ hb,
    double* __restrict__ logits, double* __restrict__ deltas)
{
    __shared__ double Ls[HPX][257];
    const int t  = threadIdx.x;
    const int p0 = blockIdx.x * HPX;
    const int b  = blockIdx.y;
#pragma unroll
    for (int r = 0; r < 32; ++r) {
        int e = t + 128 * r;
        int pxl = e >> 8, c = e & 255;
        int p = p0 + pxl;
        Ls[pxl][c] = (p < PIX) ? rpn[((size_t)b * PIX + p) * 256 + c] : 0.0;
    }
    __syncthreads();
    int pxl = t >> 3, j = t & 7;
    int p = p0 + pxl;
    if (p < PIX) {
        for (int k = 0; k < 6; ++k) {
            int oc = j + 8 * k;
            double s = (double)hb[oc];
            for (int c = 0; c < 256; ++c)
                s += Ls[pxl][c] * (double)wh[c * 48 + oc];
            if (oc < 9)
                logits[(size_t)b * NANCH + p * 9 + oc] = s;
            else if (oc < 45)
                deltas[(size_t)b * NANCH * 4 + p * 36 + (oc - 9)] = s;
        }
    }
}

// ---------------------------------------------------------------- decode [verified numerics] + hist1
__global__ void decode_anchors(
    const double* __restrict__ logits, const double* __restrict__ deltas,
    const int* __restrict__ shapes,
    double* __restrict__ boxes, u32* __restrict__ validf, u64* __restrict__ km,
    u32* __restrict__ hist1)
{
    int gid = blockIdx.x * 256 + threadIdx.x;
    if (gid >= NIMG * NANCH) return;
    int b = gid / NANCH, idx = gid - b * NANCH;
    int p = idx / 9, a = idx - p * 9;
    int y = p / 100, x = p - y * 100;
    int si = a % 3, ri = a / 3;
    double scale = (si == 0) ? 128.0 : ((si == 1) ? 256.0 : 512.0);
    double ratio = (ri == 0) ? 0.5 : ((ri == 1) ? 1.0 : 2.0);
    double hr = sqrt(ratio), wr = 1.0 / hr;
    double wsv = wr * scale, hsv = hr * scale;
    double sx = x * 16.0, sy = y * 16.0;
    double ax1 = sx + rint(-wsv * 0.5), ay1 = sy + rint(-hsv * 0.5);
    double ax2 = sx + rint(wsv * 0.5),  ay2 = sy + rint(hsv * 0.5);
    double wa = ax2 - ax1, ha = ay2 - ay1;
    double cxa = ax1 + 0.5 * wa, cya = ay1 + 0.5 * ha;
    double4 d = *(const double4*)&deltas[((size_t)b * NANCH + idx) * 4];
    float dxf = (float)d.x, dyf = (float)d.y;
    float dwf = fminf((float)d.z, (float)BBOX_CLIP_D);
    float dhf = fminf((float)d.w, (float)BBOX_CLIP_D);
    double cx = (double)dxf * wa + cxa, cy = (double)dyf * ha + cya;
    double w = exp((double)dwf) * wa, h = exp((double)dhf) * ha;
    double x1 = cx - 0.5 * w, y1 = cy - 0.5 * h, x2 = cx + 0.5 * w, y2 = cy + 0.5 * h;
    double him = (double)shapes[b * 2 + 0], wim = (double)shapes[b * 2 + 1];
    x1 = fmin(fmax(x1, 0.0), wim); y1 = fmin(fmax(y1, 0.0), him);
    x2 = fmin(fmax(x2, 0.0), wim); y2 = fmin(fmax(y2, 0.0), him);
    u32 valid = ((x2 - x1 >= 16.0) && (y2 - y1 >= 16.0)) ? 1u : 0u;
    float l32 = (float)logits[(size_t)b * NANCH + idx];
    float e32 = (float)exp(-(double)l32);
    float den = 1.0f + e32;
    float s32 = 1.0f / den;
    u32 kh = __float_as_uint(s32);
    double4 bx; bx.x = x1; bx.y = y1; bx.z = x2; bx.w = y2;
    *(double4*)&boxes[((size_t)b * NANCH + idx) * 4] = bx;
    validf[gid] = valid;
    km[gid] = ((u64)kh << 32) | (u32)(~(u32)idx);
    atomicAdd(&hist1[b * 65536 + (kh >> 16)], 1u);
}

// ---------------------------------------------------------------- two-level radix threshold
__global__ __launch_bounds__(1024) void scan_hist(const u32* __restrict__ hist, u32* scal, int level)
{
    __shared__ u32 part[1024];
    int b = blockIdx.x, t = threadIdx.x;
    const u32* h = hist + b * 65536;
    u32 s = 0;
    for (int c = 0; c < 64; ++c) s += h[t * 64 + c];
    part[t] = s; __syncthreads();
    for (int d = 1; d < 1024; d <<= 1) {
        u32 v = part[t] + ((t + d < 1024) ? part[t + d] : 0u);
        __syncthreads(); part[t] = v; __syncthreads();
    }
    u32 base  = (level == 1) ? 0u : scal[2 + b];
    u32 sfx1  = (t < 1023) ? part[t + 1] : 0u;
    u32 above = base + sfx1;
    u32 mine  = part[t] - sfx1;
    if (above < PRENMS_N && above + mine >= PRENMS_N) {
        u32 cum = above;
        for (int c = 63; c >= 0; --c) {
            u32 hv = h[t * 64 + c];
            if (cum + hv >= PRENMS_N) {
                int bin = t * 64 + c;
                if (level == 1) { scal[0 + b] = (u32)bin; scal[2 + b] = cum; }
                else            { scal[4 + b] = (scal[0 + b] << 16) | (u32)bin; scal[6 + b] = cum; }
                break;
            }
            cum += hv;
        }
    }
}

__global__ void build_hist2(const u64* __restrict__ km, const u32* __restrict__ scal,
                            u32* __restrict__ hist2)
{
    int gid = blockIdx.x * 256 + threadIdx.x;
    if (gid >= NIMG * NANCH) return;
    int b = gid / NANCH;
    u32 kh = (u32)(km[gid] >> 32);
    if ((kh >> 16) == scal[0 + b])
        atomicAdd(&hist2[b * 65536 + (kh & 0xFFFFu)], 1u);
}

__global__ void compact_cand(const u64* __restrict__ km, u32* scal, u64* __restrict__ ck)
{
    int gid = blockIdx.x * 256 + threadIdx.x;
    if (gid >= NIMG * NANCH) return;
    int b = gid / NANCH;
    u64 key = km[gid];
    u32 kh = (u32)(key >> 32);
    if (kh >= scal[4 + b]) {
        u32 pos = atomicAdd(&scal[8 + b], 1u);
        if (pos < CAND_CAP) ck[(size_t)b * CAND_CAP + pos] = key;
    }
}

// ---------------------------------------------------------------- bitonic sort 4096 + select
__global__ __launch_bounds__(1024) void sort_select(
    const u64* __restrict__ ck, const u32* __restrict__ scal,
    const double* __restrict__ boxes, const u32* __restrict__ validf,
    double* __restrict__ selbox, u32* __restrict__ selvl,
    u64* __restrict__ selkey, u32* __restrict__ selidx)
{
    __shared__ u64 sk[4096];
    int b = blockIdx.x, t = threadIdx.x;
    u32 n = scal[8 + b]; if (n > CAND_CAP) n = CAND_CAP;
    for (int i = t; i < 4096; i += 1024)
        sk[i] = (i < (int)n) ? ck[(size_t)b * CAND_CAP + i] : 0ull;
    __syncthreads();
    for (int k = 2; k <= 4096; k <<= 1) {
        for (int j = k >> 1; j > 0; j >>= 1) {
            for (int u2 = t; u2 < 2048; u2 += 1024) {
                int i  = (u2 / j) * (2 * j) + (u2 % j);
                int p2 = i + j;
                bool up = ((i & k) == 0);
                u64 ka = sk[i], kc = sk[p2];
                bool sw = up ? (kc > ka) : (ka > kc);
                if (sw) { sk[i] = kc; sk[p2] = ka; }
            }
            __syncthreads();
        }
    }
    for (int e = t; e < PRENMS_N; e += 1024) {
        u64 key = sk[e];
        u32 idx = ~(u32)key;
        selkey[b * 2048 + e] = key;
        u32 g = (idx >= NANCH) ? 0u : idx;
        selidx[b * 2048 + e] = g;
        double4 bx = *(const double4*)&boxes[((size_t)b * NANCH + g) * 4];
        *(double4*)&selbox[((size_t)b * 2048 + e) * 4] = bx;
        selvl[b * 2048 + e] = (idx >= NANCH) ? 0u : validf[(size_t)b * NANCH + g];
    }
    for (int e = PRENMS_N + t; e < 2048; e += 1024) {
        double4 z; z.x = 0.0; z.y = 0.0; z.z = 0.0; z.w = 0.0;
        *(double4*)&selbox[((size_t)b * 2048 + e) * 4] = z;
        selvl[b * 2048 + e] = 0u;
        selkey[b * 2048 + e] = 0ull;
        selidx[b * 2048 + e] = 0u;
    }
}

// ---------------------------------------------------------------- IoU mask rows (f64)
__global__ __launch_bounds__(256) void iou_mask(
    const double* __restrict__ selbox, u32* __restrict__ mask)
{
    int b = blockIdx.y, rg = blockIdx.x, t = threadIdx.x;
    int r  = rg * 64 + (t >> 2);
    int w0 = (t & 3) * 16;
    double4 bi = *(const double4*)&selbox[((size_t)b * 2048 + r) * 4];
    double ai = (bi.z - bi.x) * (bi.w - bi.y);
    for (int w = w0; w < w0 + 16; ++w) {
        u32 bits = 0;
        for (int bb = 0; bb < 32; ++bb) {
            int j = w * 32 + bb;
            double4 bj = *(const double4*)&selbox[((size_t)b * 2048 + j) * 4];
            double aj = (bj.z - bj.x) * (bj.w - bj.y);
            double lx = fmax(bi.x, bj.x), ly = fmax(bi.y, bj.y);
            double rx = fmin(bi.z, bj.z), ry = fmin(bi.w, bj.w);
            double iw = fmax(rx - lx, 0.0), ih = fmax(ry - ly, 0.0);
            double inter = iw * ih;
            double iou = inter / (ai + aj - inter + 1e-9);
            bits |= (u32)((iou > 0.7) && (j > r)) << bb;
        }
        mask[((size_t)b * 2048 + r) * 64 + w] = bits;
    }
}

// ---------------------------------------------------------------- wave bit-scan NMS (verified fixpoint)
#define NMS_STEP(i, row) { \
    u32 wv = (u32)__shfl((int)rem, (i) >> 5, 64); \
    u32 alive = ((wv >> ((i) & 31)) & 1u) ^ 1u; \
    rem |= (alive ? (row) : 0u); }

__global__ __launch_bounds__(64) void nms_scan(
    const u32* __restrict__ mask, const u32* __restrict__ selvl, u32* __restrict__ kept)
{
    int b = blockIdx.x, lane = threadIdx.x;
    u32 rem = 0;
    for (int bb = 0; bb < 32; ++bb) {
        int e = lane * 32 + bb;
        u32 s = 1u;
        if (e < PRENMS_N) s = selvl[b * 2048 + e] ? 0u : 1u;
        rem |= s << bb;
    }
    const u32* mrow = mask + (size_t)b * 2048 * 64;
    u32 f0 = mrow[0 * 64 + lane], f1 = mrow[1 * 64 + lane], f2 = mrow[2 * 64 + lane], f3 = mrow[3 * 64 + lane];
    u32 f4 = mrow[4 * 64 + lane], f5 = mrow[5 * 64 + lane], f6 = mrow[6 * 64 + lane], f7 = mrow[7 * 64 + lane];
    for (int i0 = 0; i0 < PRENMS_N; i0 += 8) {
        int nb = i0 + 8;
        u32 n0 = mrow[min(nb + 0, 1999) * 64 + lane];
        u32 n1 = mrow[min(nb + 1, 1999) * 64 + lane];
        u32 n2 = mrow[min(nb + 2, 1999) * 64 + lane];
        u32 n3 = mrow[min(nb + 3, 1999) * 64 + lane];
        u32 n4 = mrow[min(nb + 4, 1999) * 64 + lane];
        u32 n5 = mrow[min(nb + 5, 1999) * 64 + lane];
        u32 n6 = mrow[min(nb + 6, 1999) * 64 + lane];
        u32 n7 = mrow[min(nb + 7, 1999) * 64 + lane];
        NMS_STEP(i0 + 0, f0); NMS_STEP(i0 + 1, f1); NMS_STEP(i0 + 2, f2); NMS_STEP(i0 + 3, f3);
        NMS_STEP(i0 + 4, f4); NMS_STEP(i0 + 5, f5); NMS_STEP(i0 + 6, f6); NMS_STEP(i0 + 7, f7);
        f0 = n0; f1 = n1; f2 = n2; f3 = n3; f4 = n4; f5 = n5; f6 = n6; f7 = n7;
    }
    for (int bb = 0; bb < 32; ++bb) {
        int e = lane * 32 + bb;
        kept[b * 2048 + e] = (e < PRENMS_N && !((rem >> bb) & 1u)) ? 1u : 0u;
    }
}

// ---------------------------------------------------------------- finalize (popcount-parallel; same semantics)
__global__ __launch_bounds__(256) void finalize_pp(
    const u32* __restrict__ kept, const u64* __restrict__ selkey, const u32* __restrict__ selidx,
    const double* __restrict__ boxes, float* __restrict__ out)
{
    __shared__ u32 kw[64], kbase[64], sbase[64];
    __shared__ u32 nkS;
    int b = blockIdx.x, t = threadIdx.x;
    if (t < 64) {
        u32 bits = 0;
        for (int bb = 0; bb < 32; ++bb) {
            int e = t * 32 + bb;
            if (e < PRENMS_N && kept[b * 2048 + e]) bits |= 1u << bb;
        }
        kw[t] = bits;
    }
    __syncthreads();
    if (t == 0) {
        u32 ckn = 0, cs = 0;
        for (int w = 0; w < 64; ++w) {
            int valid_in_word = (w < 62) ? 32 : ((w == 62) ? 16 : 0);   // e<2000
            kbase[w] = ckn; ckn += __popc(kw[w]);
            sbase[w] = cs;  cs  += (u32)valid_in_word - __popc(kw[w]);
        }
        nkS = ckn;
    }
    __syncthreads();
    u32 nk = nkS;
    for (int e = t; e < PRENMS_N; e += 256) {
        int w = e >> 5, bb = e & 31;
        u32 low = (bb == 0) ? 0u : ((1u << bb) - 1u);
        bool isk = (kw[w] >> bb) & 1u;
        u32 r = isk ? (kbase[w] + __popc(kw[w] & low))
                    : (nk + sbase[w] + (u32)bb - __popc(kw[w] & low) - (u32)__popc(~kw[w] & low & ~(((w==62)&&0) ? 0u:0u)) * 0u);
        // suppressed rank within word = count of suppressed bits below bb = bb - popc(kept low)
        if (!isk) r = nk + sbase[w] + ((u32)bb - __popc(kw[w] & low));
        if (r < TOPK_N) {
            u32 idx = selidx[b * 2048 + e];
            double4 bx = *(const double4*)&boxes[((size_t)b * NANCH + idx) * 4];
            float4 fo = make_float4((float)bx.x, (float)bx.y, (float)bx.z, (float)bx.w);
            *(float4*)&out[((size_t)b * TOPK_N + r) * 4] = fo;
            float sc = isk ? __uint_as_float((u32)(selkey[b * 2048 + e] >> 32)) : -1.0f;
            out[(size_t)NIMG * TOPK_N * 4 + b * TOPK_N + r] = sc;
        }
    }
}

// ---------------------------------------------------------------- host-error flood
__global__ void flood(float* __restrict__ out, u32 hostbits)
{
    if (hostbits == 0u) return;
    int bit = __ffs(hostbits) - 1;
    float c = 60000.f + 4000.f * (float)bit;
    int i = blockIdx.x * 256 + threadIdx.x;
    if (i < NIMG * TOPK_N * 5) out[i] = c;
}

// ================================================================ launch
extern "C" void kernel_launch(void* const* d_in, const int* in_sizes, int n_in,
                              void* d_out, int out_size, void* d_ws, size_t ws_size,
                              hipStream_t stream)
{
    float* out = (float*)d_out;
    char* ws = (char*)d_ws;

    const float *feat = nullptr, *conv_w = nullptr, *conv_b = nullptr;
    const float *cls_w = nullptr, *cls_b = nullptr, *box_w = nullptr, *box_b = nullptr;
    const int* shapes = nullptr;
    for (int i = 0; i < n_in; ++i) {
        switch (in_sizes[i]) {
            case 5120000:  feat   = (const float*)d_in[i]; break;
            case 4:        shapes = (const int*)d_in[i]; break;
            case 589824:   conv_w = (const float*)d_in[i]; break;
            case 256:      conv_b = (const float*)d_in[i]; break;
            case 2304:     cls_w  = (const float*)d_in[i]; break;
            case 9:        cls_b  = (const float*)d_in[i]; break;
            case 9216:     box_w  = (const float*)d_in[i]; break;
            case 36:       box_b  = (const float*)d_in[i]; break;
            default: break;
        }
    }
    u32 hostbits = 0;
    if (!feat || !shapes || !conv_w || !conv_b || !cls_w || !cls_b || !box_w || !box_b)
        hostbits |= 2u;

    size_t off = 0;
    auto take = [&](size_t bytes) { size_t o = off; off += (bytes + 255) & ~(size_t)255; return o; };
    size_t off_wt     = take((size_t)2304 * 256 * 4);
    size_t off_wh     = take((size_t)256 * 48 * 4);
    size_t off_hb     = take(256);
    size_t off_rpn    = take((size_t)NIMG * PIX * 256 * 8);
    size_t off_logit  = take((size_t)NIMG * NANCH * 8);
    size_t off_delta  = take((size_t)NIMG * NANCH * 4 * 8);
    size_t off_boxes  = take((size_t)NIMG * NANCH * 4 * 8);
    size_t off_valid  = take((size_t)NIMG * NANCH * 4);
    size_t off_km     = take((size_t)NIMG * NANCH * 8);
    size_t off_hist1  = take((size_t)NIMG * 65536 * 4);
    size_t off_hist2  = take((size_t)NIMG * 65536 * 4);
    size_t off_scal   = take(256);
    size_t off_ck     = take((size_t)NIMG * CAND_CAP * 8);
    size_t off_selbox = take((size_t)NIMG * 2048 * 4 * 8);
    size_t off_selvl  = take((size_t)NIMG * 2048 * 4);
    size_t off_selkey = take((size_t)NIMG * 2048 * 8);
    size_t off_selidx = take((size_t)NIMG * 2048 * 4);
    size_t off_mask   = take((size_t)NIMG * 2048 * 64 * 4);
    size_t off_kept   = take((size_t)NIMG * 2048 * 4);
    if (ws_size < off) hostbits |= 1u;

    float*  wt     = (float*) (ws + off_wt);
    float*  wh     = (float*) (ws + off_wh);
    float*  hb     = (float*) (ws + off_hb);
    double* rpn    = (double*)(ws + off_rpn);
    double* logit  = (double*)(ws + off_logit);
    double* delta  = (double*)(ws + off_delta);
    double* boxes  = (double*)(ws + off_boxes);
    u32*    validf = (u32*)   (ws + off_valid);
    u64*    km     = (u64*)   (ws + off_km);
    u32*    hist1  = (u32*)   (ws + off_hist1);
    u32*    hist2  = (u32*)   (ws + off_hist2);
    u32*    scal   = (u32*)   (ws + off_scal);
    u64*    ck     = (u64*)   (ws + off_ck);
    double* selbox = (double*)(ws + off_selbox);
    u32*    selvl  = (u32*)   (ws + off_selvl);
    u64*    selkey = (u64*)   (ws + off_selkey);
    u32*    selidx = (u32*)   (ws + off_selidx);
    u32*    mask   = (u32*)   (ws + off_mask);
    u32*    kept   = (u32*)   (ws + off_kept);

    if (hostbits != 0) {
        flood<<<40, 256, 0, stream>>>(out, hostbits);
        return;
    }

    hipMemsetAsync(ws + off_hist1, 0, off_ck - off_hist1, stream);

    prep_weights<<<(2304 * 256 + 256 * 48 + 48 + 255) / 256, 256, 0, stream>>>(
        conv_w, cls_w, box_w, cls_b, box_b, wt, wh, hb);

    conv3x3<<<dim3((PIX + TP - 1) / TP, 2, NIMG), 256, 0, stream>>>(feat, wt, conv_b, rpn);

    heads<<<dim3((PIX + HPX - 1) / HPX, NIMG), 128, 0, stream>>>(rpn, wh, hb, logit, delta);

    decode_anchors<<<(NIMG * NANCH + 255) / 256, 256, 0, stream>>>(
        logit, delta, shapes, boxes, validf, km, hist1);

    scan_hist<<<NIMG, 1024, 0, stream>>>(hist1, scal, 1);
    build_hist2<<<(NIMG * NANCH + 255) / 256, 256, 0, stream>>>(km, scal, hist2);
    scan_hist<<<NIMG, 1024, 0, stream>>>(hist2, scal, 2);
    compact_cand<<<(NIMG * NANCH + 255) / 256, 256, 0, stream>>>(km, scal, ck);

    sort_select<<<NIMG, 1024, 0, stream>>>(ck, scal, boxes, validf,
                                           selbox, selvl, selkey, selidx);

    iou_mask<<<dim3(32, NIMG), 256, 0, stream>>>(selbox, mask);
    nms_scan<<<NIMG, 64, 0, stream>>>(mask, selvl, kept);

    finalize_pp<<<NIMG, 256, 0, stream>>>(kept, selkey, selidx, boxes, out);
}